// Round 4
// baseline (1689.090 us; speedup 1.0000x reference)
//
#include <hip/hip_runtime.h>
#include <hip/hip_bf16.h>
#include <math.h>
#include <stdint.h>

namespace {

constexpr int Bn  = 8;
constexpr int Nn  = 500;
constexpr int Qn  = 25;
constexpr int ENC = 512;
constexpr int DIN = 300;
constexpr int NCn = 70;
constexpr int NETn = 3;

typedef __attribute__((ext_vector_type(8))) short bf16x8_t;
typedef __attribute__((ext_vector_type(4))) float f32x4_t;

__device__ __forceinline__ unsigned short f2bf(float f) {
    union { __hip_bfloat16 b; unsigned short u; } r;
    r.b = __float2bfloat16(f);
    return r.u;
}
__device__ __forceinline__ bf16x8_t cvt8(float4 f0, float4 f1) {
    union { bf16x8_t v; __hip_bfloat162 b[4]; } r;
    r.b[0] = __float22bfloat162_rn(make_float2(f0.x, f0.y));
    r.b[1] = __float22bfloat162_rn(make_float2(f0.z, f0.w));
    r.b[2] = __float22bfloat162_rn(make_float2(f1.x, f1.y));
    r.b[3] = __float22bfloat162_rn(make_float2(f1.z, f1.w));
    return r.v;
}
__device__ __forceinline__ float bf2f(unsigned short h) {
    unsigned int u = ((unsigned int)h) << 16;
    return __builtin_bit_cast(float, u);
}
__device__ __forceinline__ float sigmoidf_(float x) { return 1.0f / (1.0f + expf(-x)); }

// ---------------------------------------------------------------------------
// R19: self-managed grid barrier (graph-capture-safe, explicit agent-scope
// release/acquire).  bar[0]=arrival cnt, bar[32]=generation (separate lines).
// State zeroed by hipMemsetAsync at the top of kernel_launch each replay.
__device__ __forceinline__ void gbar(unsigned int* bar, unsigned int nb) {
    __syncthreads();
    if (threadIdx.x == 0) {
        unsigned int* cnt = bar;
        unsigned int* gen = bar + 32;
        __threadfence();
        unsigned int g = __hip_atomic_load(gen, __ATOMIC_ACQUIRE, __HIP_MEMORY_SCOPE_AGENT);
        unsigned int old = __hip_atomic_fetch_add(cnt, 1u, __ATOMIC_ACQ_REL, __HIP_MEMORY_SCOPE_AGENT);
        if (old == nb - 1u) {
            __hip_atomic_store(cnt, 0u, __ATOMIC_RELAXED, __HIP_MEMORY_SCOPE_AGENT);
            __hip_atomic_fetch_add(gen, 1u, __ATOMIC_RELEASE, __HIP_MEMORY_SCOPE_AGENT);
        } else {
            while (__hip_atomic_load(gen, __ATOMIC_ACQUIRE, __HIP_MEMORY_SCOPE_AGENT) == g) {
                __builtin_amdgcn_s_sleep(2);
            }
        }
        __threadfence();
    }
    __syncthreads();
}

// ---------------------------------------------------------------------------
// Fused prep: z=1 -> Asum; z=0 -> all weight transposes.
__global__ __launch_bounds__(256) void prep_k(
    const float* __restrict__ adj, float* __restrict__ Asum,
    const float* __restrict__ Wn, const float* __restrict__ Wq,
    const float* __restrict__ Wh, const float* __restrict__ Wc,
    const float* __restrict__ W1,
    unsigned short* __restrict__ WnT, unsigned short* __restrict__ WqT,
    unsigned short* __restrict__ WhcT, unsigned short* __restrict__ WcHiT,
    unsigned short* __restrict__ W1T) {
    if (blockIdx.z == 1) {
        int bi = blockIdx.x * 2 + (threadIdx.x >> 7);
        if (bi >= Bn * Nn) return;
        int b = bi / Nn, i = bi - b * Nn;
        int j = (threadIdx.x & 127) * 4;
        float4 s = make_float4(0.f, 0.f, 0.f, 0.f);
        if (j < Nn) {
#pragma unroll
            for (int e = 0; e < NETn; ++e) {
                const float* p = adj + (((size_t)(b * NETn + e) * Nn) + i) * Nn + j;
                float4 v = *(const float4*)p;
                s.x += v.x; s.y += v.y; s.z += v.z; s.w += v.w;
            }
        }
        *(float4*)(Asum + ((size_t)bi) * 512 + j) = s;
        return;
    }
    __shared__ float tile[32][33];
    int x = blockIdx.x;
    const float* in; unsigned short* out; int K, N, Kpad, tx, ty;
    if (x < 160)       { in = Wn; out = WnT; K = DIN; N = ENC; Kpad = 320;
                         tx = x & 15; ty = x >> 4; }
    else if (x < 320)  { int l = x - 160; in = Wq; out = WqT; K = DIN; N = ENC;
                         Kpad = 320; tx = l & 15; ty = l >> 4; }
    else if (x < 576)  { int l = x - 320; in = Wh; out = WhcT; K = 512; N = ENC;
                         Kpad = 512; tx = l & 15; ty = l >> 4; }
    else if (x < 832)  { int l = x - 576; in = Wc + (size_t)512 * ENC;
                         out = WhcT + (size_t)512 * 512; K = 512; N = ENC;
                         Kpad = 512; tx = l & 15; ty = l >> 4; }
    else if (x < 1088) { int l = x - 832; in = Wc; out = WcHiT; K = 512; N = ENC;
                         Kpad = 512; tx = l & 15; ty = l >> 4; }
    else if (x < 1344) { int l = x - 1088; in = W1; out = W1T; K = 2048; N = 128;
                         Kpad = 2048; tx = l & 3; ty = l >> 2; }
    else return;
    int n0 = tx * 32, k0 = ty * 32;
    int ltx = threadIdx.x & 31, lty = threadIdx.x >> 5;
#pragma unroll
    for (int r = 0; r < 4; ++r) {
        int k = k0 + lty * 4 + r;
        int n = n0 + ltx;
        tile[lty * 4 + r][ltx] = (k < K && n < N) ? in[(size_t)k * N + n] : 0.0f;
    }
    __syncthreads();
#pragma unroll
    for (int r = 0; r < 4; ++r) {
        int n = n0 + lty * 4 + r;
        int k = k0 + ltx;
        if (n < N && k < Kpad) out[(size_t)n * Kpad + k] = f2bf(tile[ltx][lty * 4 + r]);
    }
}

// ---------------------------------------------------------------------------
// MFMA core, BK=64: 64x64 tile, 4 waves, double-buffered LDS.
// AMODE 0: A fp32 (Klim clamp).  AMODE 1: A bf16.  Bt: bf16 B^T [n][k].
template <int AMODE>
__device__ __forceinline__ void mfma_core(
    const float* __restrict__ A,
    const unsigned short* __restrict__ Abf,
    int lda, int Klim,
    const unsigned short* __restrict__ Bt, int ldb,
    int m0, int n0, int K, int Mlim,
    unsigned short* As, unsigned short* Bts, f32x4_t acc[2][2]) {
    const int t = threadIdx.x;
    const int lane = t & 63;
    const int w = t >> 6;
    const int sm = t >> 2;
    const int sp = t & 3;
    const int sq = sp ^ ((sm >> 1) & 3);
    const int arow = m0 + sm;
    const bool rowok = arow < Mlim;
    const int wm = (w & 1) * 32, wn = (w >> 1) * 32;
    const int quad = lane >> 4, cidx = lane & 15;
    const int am0 = wm + cidx, am1 = wm + 16 + cidx;
    const int an0 = wn + cidx, an1 = wn + 16 + cidx;
    const int apo0 = am0 * 32 + (quad ^ ((am0 >> 1) & 3)) * 8;
    const int apo1 = am1 * 32 + (quad ^ ((am1 >> 1) & 3)) * 8;
    const int bpo0 = an0 * 32 + (quad ^ ((an0 >> 1) & 3)) * 8;
    const int bpo1 = an1 * 32 + (quad ^ ((an1 >> 1) & 3)) * 8;

    bf16x8_t ast0, ast1, bst0, bst1;
    auto stageA = [&](int kg) -> bf16x8_t {
        if (AMODE == 1) {
            bf16x8_t r = {0, 0, 0, 0, 0, 0, 0, 0};
            if (rowok) r = *(const bf16x8_t*)(Abf + (size_t)arow * lda + kg);
            return r;
        } else {
            float4 f0 = make_float4(0.f, 0.f, 0.f, 0.f);
            float4 f1 = make_float4(0.f, 0.f, 0.f, 0.f);
            if (rowok) {
                const float* src = A + (size_t)arow * lda + kg;
                if (kg + 8 <= Klim) {
                    f0 = *(const float4*)src;
                    f1 = *(const float4*)(src + 4);
                } else if (kg + 4 <= Klim) {
                    f0 = *(const float4*)src;
                }
            }
            return cvt8(f0, f1);
        }
    };
    auto stage = [&](int k0) {
        int kg0 = k0 + sq * 8;
        int kg1 = k0 + 32 + sq * 8;
        ast0 = stageA(kg0);
        ast1 = stageA(kg1);
        const unsigned short* brow = Bt + (size_t)(n0 + sm) * ldb;
        bst0 = *(const bf16x8_t*)(brow + kg0);
        bst1 = *(const bf16x8_t*)(brow + kg1);
    };

    const int ktot = K >> 6;
    stage(0);
    *(bf16x8_t*)(As + t * 8) = ast0;
    *(bf16x8_t*)(As + 2048 + t * 8) = ast1;
    *(bf16x8_t*)(Bts + t * 8) = bst0;
    *(bf16x8_t*)(Bts + 2048 + t * 8) = bst1;
    for (int kt = 0; kt < ktot; ++kt) {
        __syncthreads();
        const int cur = (kt & 1) * 4096;
        const bool more = (kt + 1) < ktot;
        if (more) stage((kt + 1) << 6);
        {
            bf16x8_t a0 = *(const bf16x8_t*)(As + cur + apo0);
            bf16x8_t a1 = *(const bf16x8_t*)(As + cur + apo1);
            bf16x8_t b0 = *(const bf16x8_t*)(Bts + cur + bpo0);
            bf16x8_t b1 = *(const bf16x8_t*)(Bts + cur + bpo1);
            acc[0][0] = __builtin_amdgcn_mfma_f32_16x16x32_bf16(a0, b0, acc[0][0], 0, 0, 0);
            acc[0][1] = __builtin_amdgcn_mfma_f32_16x16x32_bf16(a0, b1, acc[0][1], 0, 0, 0);
            acc[1][0] = __builtin_amdgcn_mfma_f32_16x16x32_bf16(a1, b0, acc[1][0], 0, 0, 0);
            acc[1][1] = __builtin_amdgcn_mfma_f32_16x16x32_bf16(a1, b1, acc[1][1], 0, 0, 0);
        }
        {
            bf16x8_t a0 = *(const bf16x8_t*)(As + cur + 2048 + apo0);
            bf16x8_t a1 = *(const bf16x8_t*)(As + cur + 2048 + apo1);
            bf16x8_t b0 = *(const bf16x8_t*)(Bts + cur + 2048 + bpo0);
            bf16x8_t b1 = *(const bf16x8_t*)(Bts + cur + 2048 + bpo1);
            acc[0][0] = __builtin_amdgcn_mfma_f32_16x16x32_bf16(a0, b0, acc[0][0], 0, 0, 0);
            acc[0][1] = __builtin_amdgcn_mfma_f32_16x16x32_bf16(a0, b1, acc[0][1], 0, 0, 0);
            acc[1][0] = __builtin_amdgcn_mfma_f32_16x16x32_bf16(a1, b0, acc[1][0], 0, 0, 0);
            acc[1][1] = __builtin_amdgcn_mfma_f32_16x16x32_bf16(a1, b1, acc[1][1], 0, 0, 0);
        }
        if (more) {
            const int nxt = ((kt + 1) & 1) * 4096;
            *(bf16x8_t*)(As + nxt + t * 8) = ast0;
            *(bf16x8_t*)(As + nxt + 2048 + t * 8) = ast1;
            *(bf16x8_t*)(Bts + nxt + t * 8) = bst0;
            *(bf16x8_t*)(Bts + nxt + 2048 + t * 8) = bst1;
        }
    }
}

#define EPI_SETUP                                         \
    int t = threadIdx.x, lane = t & 63, w = t >> 6;       \
    int wm = (w & 1) * 32, wn = (w >> 1) * 32;            \
    int quad = lane >> 4, cidx = lane & 15;               \
    (void)wm; (void)wn; (void)quad; (void)cidx;

// R17: tile fully dead iff single-batch tile with i0 >= lens[b].
__device__ __forceinline__ bool tile_dead(int m0, const int* __restrict__ lens) {
    int bA = m0 / Nn;
    int lastRow = m0 + 63;
    if (lastRow >= Bn * Nn) lastRow = Bn * Nn - 1;
    int bB = lastRow / Nn;
    return (bA == bB) && ((m0 - bA * Nn) >= lens[bA]);
}

// ---------------------------------------------------------------------------
// R18/R19 mega kernel: gemm_in -> 3x(hmw, upd, att) -> sim, with software
// grid barriers (gbar) instead of cg::grid_group (graph-capture-safe).
// 512 blocks x 256 thr; __launch_bounds__(256,2) -> VGPR<=256 -> >=2
// blocks/CU; LDS 50.2KB -> 3 blocks/CU; 512 blocks all co-resident.
// Asum/n2q alias (phase-separated) -> no __restrict__ on them.
__global__ __launch_bounds__(256, 2) void mega_k(
    const float* ng, const float* qg,
    const unsigned short* WnT, const unsigned short* WqT,
    const float* bn, const float* bq, const int* lens,
    float* nc, unsigned short* lh0, float* qc,
    const float* Asum, const unsigned short* WhcT, const unsigned short* WcHiT,
    const float* bh, const float* bc,
    unsigned short* hm, unsigned short* upd, float* pa, unsigned short* lh1,
    const float* wa, float* n2q, float* rowmax, unsigned int* bar) {
    const unsigned int NB = gridDim.x;
    __shared__ __align__(16) unsigned char smem[51328];
    unsigned short* As  = (unsigned short*)smem;           // 8192 shorts
    unsigned short* Bts = (unsigned short*)(smem + 16384); // 8192 shorts

    // ---- P0: fused input GEMMs (67x8 = 536 tiles) ----
    for (int idx = blockIdx.x; idx < 536; idx += gridDim.x) {
        int x = idx % 67, y = idx / 67;
        const bool isq = x >= 63;
        int m0 = (isq ? (x - 63) : x) * 64;
        int n0 = y * 64;
        const float* A = isq ? qg : ng;
        const unsigned short* Bt = isq ? WqT : WnT;
        const int Mlim = isq ? Bn * Qn : Bn * Nn;
        f32x4_t z = {0.f, 0.f, 0.f, 0.f};
        f32x4_t acc[2][2] = {{z, z}, {z, z}};
        mfma_core<0>(A, nullptr, DIN, DIN, Bt, 320, m0, n0, 320, Mlim, As, Bts, acc);
        {
            EPI_SETUP
#pragma unroll
            for (int nj = 0; nj < 2; ++nj) {
                int col = n0 + wn + nj * 16 + cidx;
                float bias = isq ? bq[col] : bn[col];
#pragma unroll
                for (int mi = 0; mi < 2; ++mi) {
#pragma unroll
                    for (int r = 0; r < 4; ++r) {
                        int row = m0 + wm + mi * 16 + quad * 4 + r;
                        if (row < Mlim) {
                            float v = acc[mi][nj][r] + bias;
                            if (isq) {
                                qc[(size_t)row * ENC + col] = v;
                            } else {
                                float tv = tanhf(v);
                                int b = row / Nn, i = row - b * Nn;
                                float rm = (i < lens[b]) ? 1.0f : 0.0f;
                                nc[(size_t)row * ENC + col] = tv;
                                lh0[(size_t)row * ENC + col] = f2bf(tv * rm);
                            }
                        }
                    }
                }
            }
        }
        __syncthreads();  // protect LDS before next grid-stride iteration
    }
    gbar(bar, NB);

    // ---- 3 hops ----
    unsigned short* cur = lh0;
    unsigned short* nxt = lh1;
    for (int h = 0; h < 3; ++h) {
        // P1: wide hop GEMM lh @ [Wh | Wc_lo]  (63 x 16 = 1008 tiles)
        for (int idx = blockIdx.x; idx < 1008; idx += gridDim.x) {
            int xt = idx % 63, yt = idx / 63;
            int m0 = xt * 64, n0 = yt * 64;
            if (tile_dead(m0, lens)) {
                if (n0 < 512) {
                    int tt = threadIdx.x;
                    int row = m0 + (tt >> 2);
                    int cseg = (tt & 3) * 16;
                    if (row < Bn * Nn) {
                        bf16x8_t zz = {0, 0, 0, 0, 0, 0, 0, 0};
                        *(bf16x8_t*)(hm + (size_t)row * ENC + n0 + cseg) = zz;
                        *(bf16x8_t*)(hm + (size_t)row * ENC + n0 + cseg + 8) = zz;
                    }
                }
                continue;
            }
            f32x4_t z = {0.f, 0.f, 0.f, 0.f};
            f32x4_t acc[2][2] = {{z, z}, {z, z}};
            mfma_core<1>(nullptr, cur, ENC, ENC, WhcT, 512, m0, n0, ENC,
                         Bn * Nn, As, Bts, acc);
            {
                EPI_SETUP
#pragma unroll
                for (int nj = 0; nj < 2; ++nj) {
                    int col = n0 + wn + nj * 16 + cidx;
                    bool ishm = col < 512;
                    float bias = ishm ? bh[col] : 0.0f;
#pragma unroll
                    for (int mi = 0; mi < 2; ++mi) {
#pragma unroll
                        for (int r = 0; r < 4; ++r) {
                            int row = m0 + wm + mi * 16 + quad * 4 + r;
                            if (row < Bn * Nn) {
                                int b = row / Nn, i = row - b * Nn;
                                float rm = (i < lens[b]) ? 1.0f : 0.0f;
                                float v = acc[mi][nj][r];
                                if (ishm) {
                                    hm[(size_t)row * ENC + col] = f2bf((v + bias) * rm);
                                } else {
                                    pa[(size_t)row * ENC + (col - 512)] = v;
                                }
                            }
                        }
                    }
                }
            }
            __syncthreads();
        }
        gbar(bar, NB);

        // P2: sparse aggregation (1000 row-quads)
        for (int idx = blockIdx.x; idx < 1000; idx += gridDim.x) {
            int wv = threadIdx.x >> 6, lane = threadIdx.x & 63;
            int row = idx * 4 + wv;
            int b = row / Nn, i = row - b * Nn;
            int d0 = lane * 8;
            if (i >= lens[b]) {
                bf16x8_t zz = {0, 0, 0, 0, 0, 0, 0, 0};
                *(bf16x8_t*)(upd + (size_t)row * ENC + d0) = zz;
            } else {
                const float* arow = Asum + (size_t)row * 512;
                const unsigned short* hmb = hm + (size_t)b * Nn * ENC;
                float acc[8];
                {
                    bf16x8_t hv = *(const bf16x8_t*)(hmb + (size_t)i * ENC + d0);
#pragma unroll
                    for (int j = 0; j < 8; ++j) acc[j] = bf2f((unsigned short)hv[j]);
                }
#pragma unroll
                for (int c = 0; c < 8; ++c) {
                    int j = c * 64 + lane;
                    float val = (j < Nn) ? arow[j] : 0.0f;
                    unsigned long long mask = __ballot(val != 0.0f);
                    while (mask) {
                        int b0 = __ffsll((unsigned long long)mask) - 1;
                        mask &= mask - 1;
                        int b1 = -1;
                        if (mask) { b1 = __ffsll((unsigned long long)mask) - 1; mask &= mask - 1; }
                        float v0 = __shfl(val, b0, 64);
                        bf16x8_t xv = *(const bf16x8_t*)(hmb + (size_t)(c * 64 + b0) * ENC + d0);
                        float v1 = 0.0f;
                        bf16x8_t yv = {0, 0, 0, 0, 0, 0, 0, 0};
                        if (b1 >= 0) {
                            v1 = __shfl(val, b1, 64);
                            yv = *(const bf16x8_t*)(hmb + (size_t)(c * 64 + b1) * ENC + d0);
                        }
#pragma unroll
                        for (int k = 0; k < 8; ++k)
                            acc[k] += v0 * bf2f((unsigned short)xv[k]) + v1 * bf2f((unsigned short)yv[k]);
                    }
                }
                float4 o0 = make_float4(acc[0], acc[1], acc[2], acc[3]);
                float4 o1 = make_float4(acc[4], acc[5], acc[6], acc[7]);
                *(bf16x8_t*)(upd + (size_t)row * ENC + d0) = cvt8(o0, o1);
            }
        }
        gbar(bar, NB);

        // P3: att GEMM + hop update (63 x 8 = 504 tiles)
        for (int idx = blockIdx.x; idx < 504; idx += gridDim.x) {
            int xt = idx % 63, yt = idx / 63;
            int m0 = xt * 64, n0 = yt * 64;
            if (tile_dead(m0, lens)) {
                int tt = threadIdx.x;
                int row = m0 + (tt >> 2);
                int cseg = (tt & 3) * 16;
                if (row < Bn * Nn) {
                    bf16x8_t zz = {0, 0, 0, 0, 0, 0, 0, 0};
                    *(bf16x8_t*)(nxt + (size_t)row * ENC + n0 + cseg) = zz;
                    *(bf16x8_t*)(nxt + (size_t)row * ENC + n0 + cseg + 8) = zz;
                }
                continue;
            }
            f32x4_t z = {0.f, 0.f, 0.f, 0.f};
            f32x4_t acc[2][2] = {{z, z}, {z, z}};
            mfma_core<1>(nullptr, upd, ENC, ENC, WcHiT, 512, m0, n0, ENC,
                         Bn * Nn, As, Bts, acc);
            {
                EPI_SETUP
#pragma unroll
                for (int nj = 0; nj < 2; ++nj) {
                    int col = n0 + wn + nj * 16 + cidx;
                    float bias = bc[col];
#pragma unroll
                    for (int mi = 0; mi < 2; ++mi) {
#pragma unroll
                        for (int r = 0; r < 4; ++r) {
                            int row = m0 + wm + mi * 16 + quad * 4 + r;
                            if (row < Bn * Nn) {
                                int b = row / Nn, i = row - b * Nn;
                                float rm = (i < lens[b]) ? 1.0f : 0.0f;
                                size_t off = (size_t)row * ENC + col;
                                float a = sigmoidf_(acc[mi][nj][r] + pa[off] + bias) * rm;
                                float u = bf2f(upd[off]);
                                float l = bf2f(cur[off]);
                                nxt[off] = f2bf(a * tanhf(u) + (1.0f - a) * l);
                            }
                        }
                    }
                }
            }
            __syncthreads();
        }
        gbar(bar, NB);
        unsigned short* tmp = cur; cur = nxt; nxt = tmp;
    }
    // cur == lh1 == final last_hop.

    // ---- P4: fused sim -> softmax(q) -> n2q + rowmax (1000 row-quads) ----
    float* qcs  = (float*)smem;            // 25*512 floats = 50KB
    float* qdot = (float*)(smem + 51200);  // 32 floats
    for (int idx = blockIdx.x; idx < 1000; idx += gridDim.x) {
        int b = idx & 7, yq = idx >> 3;
        int t = threadIdx.x;
        const float* qcb = qc + (size_t)b * Qn * ENC;
        for (int i = t * 4; i < Qn * ENC; i += 1024)
            *(float4*)&qcs[i] = *(const float4*)&qcb[i];
        __syncthreads();
        {
            int q = t >> 3, j = t & 7;
            if (q < Qn) {
                float s = 0.f;
                for (int k = 0; k < 64; ++k) {
                    int d = j + 8 * k;
                    s += qcs[q * ENC + d] * wa[ENC + d];
                }
                s += __shfl_xor(s, 1, 64);
                s += __shfl_xor(s, 2, 64);
                s += __shfl_xor(s, 4, 64);
                if (j == 0) qdot[q] = s;
            }
        }
        __syncthreads();

        int wv = t >> 6, lane = t & 63;
        int n = yq * 4 + wv;
        int dA = lane * 4;
        int dB = 256 + lane * 4;
        const bool valid = n < lens[b];

        float s_[Qn];
        if (valid) {
            const unsigned short* lrow = cur + ((size_t)b * Nn + n) * ENC;
            ushort4 ua = *(const ushort4*)(lrow + dA);
            ushort4 ub = *(const ushort4*)(lrow + dB);
            float lv[8] = {bf2f(ua.x), bf2f(ua.y), bf2f(ua.z), bf2f(ua.w),
                           bf2f(ub.x), bf2f(ub.y), bf2f(ub.z), bf2f(ub.w)};
            float ndp = 0.f;
            float lvs[8];
#pragma unroll
            for (int j = 0; j < 4; ++j) {
                ndp += lv[j] * wa[dA + j];
                lvs[j] = lv[j] * wa[2 * ENC + dA + j];
                ndp += lv[4 + j] * wa[dB + j];
                lvs[4 + j] = lv[4 + j] * wa[2 * ENC + dB + j];
            }
#pragma unroll
            for (int off = 32; off; off >>= 1) ndp += __shfl_xor(ndp, off, 64);

#pragma unroll
            for (int q = 0; q < Qn; ++q) {
                float4 qa = *(const float4*)(qcs + q * ENC + dA);
                float4 qb = *(const float4*)(qcs + q * ENC + dB);
                s_[q] = lvs[0] * qa.x + lvs[1] * qa.y + lvs[2] * qa.z + lvs[3] * qa.w +
                        lvs[4] * qb.x + lvs[5] * qb.y + lvs[6] * qb.z + lvs[7] * qb.w;
            }
#pragma unroll
            for (int q = 0; q < Qn; ++q) {
#pragma unroll
                for (int off = 32; off; off >>= 1) s_[q] += __shfl_xor(s_[q], off, 64);
            }
#pragma unroll
            for (int q = 0; q < Qn; ++q) s_[q] += ndp + qdot[q];
        } else {
#pragma unroll
            for (int q = 0; q < Qn; ++q) s_[q] = qdot[q];
        }

        float mx = -INFINITY;
#pragma unroll
        for (int q = 0; q < Qn; ++q) mx = fmaxf(mx, s_[q]);
        float sum = 0.f;
#pragma unroll
        for (int q = 0; q < Qn; ++q) { s_[q] = expf(s_[q] - mx); sum += s_[q]; }
        float inv = 1.0f / sum;
        float o[8] = {};
#pragma unroll
        for (int q = 0; q < Qn; ++q) {
            float4 qa = *(const float4*)(qcs + q * ENC + dA);
            float4 qb = *(const float4*)(qcs + q * ENC + dB);
            float p = s_[q] * inv;
            o[0] += p * qa.x; o[1] += p * qa.y; o[2] += p * qa.z; o[3] += p * qa.w;
            o[4] += p * qb.x; o[5] += p * qb.y; o[6] += p * qb.z; o[7] += p * qb.w;
        }
        float* orow = n2q + ((size_t)b * Nn + n) * ENC;
        *(float4*)(orow + dA) = make_float4(o[0], o[1], o[2], o[3]);
        *(float4*)(orow + dB) = make_float4(o[4], o[5], o[6], o[7]);
        if (lane == 0) rowmax[b * Nn + n] = mx;
        __syncthreads();  // qcs reused next iteration
    }
}

// ---------------------------------------------------------------------------
// Materialize g = [nc | n2q | nc*n2q | nc*q2n] as bf16 [4000][2048].
__global__ __launch_bounds__(256) void gbf_k(const float* __restrict__ nc,
                                             const float* __restrict__ n2q,
                                             const float* __restrict__ q2n,
                                             unsigned short* __restrict__ gbf) {
    int row = blockIdx.x;
    int b = row / Nn;
    int t = threadIdx.x;
    int seg = t >> 6;
    int d = (t & 63) * 8;
    size_t off = (size_t)row * ENC + d;
    float4 a0, a1;
    if (seg == 0) {
        a0 = *(const float4*)(nc + off); a1 = *(const float4*)(nc + off + 4);
    } else if (seg == 1) {
        a0 = *(const float4*)(n2q + off); a1 = *(const float4*)(n2q + off + 4);
    } else if (seg == 2) {
        float4 x0 = *(const float4*)(nc + off), x1 = *(const float4*)(nc + off + 4);
        float4 y0 = *(const float4*)(n2q + off), y1 = *(const float4*)(n2q + off + 4);
        a0 = make_float4(x0.x * y0.x, x0.y * y0.y, x0.z * y0.z, x0.w * y0.w);
        a1 = make_float4(x1.x * y1.x, x1.y * y1.y, x1.z * y1.z, x1.w * y1.w);
    } else {
        float4 x0 = *(const float4*)(nc + off), x1 = *(const float4*)(nc + off + 4);
        const float* qp = q2n + (size_t)b * ENC + d;
        float4 y0 = *(const float4*)qp, y1 = *(const float4*)(qp + 4);
        a0 = make_float4(x0.x * y0.x, x0.y * y0.y, x0.z * y0.z, x0.w * y0.w);
        a1 = make_float4(x1.x * y1.x, x1.y * y1.y, x1.z * y1.z, x1.w * y1.w);
    }
    *(bf16x8_t*)(gbf + (size_t)row * 2048 + seg * 512 + d) = cvt8(a0, a1);
}

// ---------------------------------------------------------------------------
// g @ W1 split-K partials via MFMA; z = K-slice in [0,4) (512 wide).
__global__ __launch_bounds__(256) void gemm_final_k(const unsigned short* __restrict__ gbf,
                                                    const unsigned short* __restrict__ W1T,
                                                    float* __restrict__ part) {
    __shared__ __align__(16) unsigned short As[8192], Bts[8192];
    f32x4_t z4 = {0.f, 0.f, 0.f, 0.f};
    f32x4_t acc[2][2] = {{z4, z4}, {z4, z4}};
    int zz = blockIdx.z;
    int m0 = blockIdx.x * 64, n0 = blockIdx.y * 64;
    mfma_core<1>(nullptr, gbf + zz * 512, 2048, 1 << 30,
                 W1T + zz * 512, 2048, m0, n0, 512, Bn * Nn, As, Bts, acc);
    EPI_SETUP
    constexpr int M = Bn * Nn;
#pragma unroll
    for (int nj = 0; nj < 2; ++nj) {
        int col = n0 + wn + nj * 16 + cidx;
#pragma unroll
        for (int mi = 0; mi < 2; ++mi) {
#pragma unroll
            for (int r = 0; r < 4; ++r) {
                int row = m0 + wm + mi * 16 + quad * 4 + r;
                if (row < M) part[((size_t)zz * M + row) * 128 + col] = acc[mi][nj][r];
            }
        }
    }
}

// ---------------------------------------------------------------------------
// Fused bvec (softmax over rowmax) + q2n (bvec-weighted sum of nc).
__global__ __launch_bounds__(512) void bvec_q2n_k(const float* __restrict__ rowmax,
                                                  const float* __restrict__ nc,
                                                  float* __restrict__ q2n) {
    __shared__ float red[8];
    __shared__ float bvs[512];
    int b = blockIdx.x, t = threadIdx.x;
    float v = (t < Nn) ? rowmax[b * Nn + t] : -INFINITY;
    float m = v;
    for (int off = 32; off; off >>= 1) m = fmaxf(m, __shfl_xor(m, off, 64));
    if ((t & 63) == 0) red[t >> 6] = m;
    __syncthreads();
    float bm = red[0];
    for (int i = 1; i < 8; ++i) bm = fmaxf(bm, red[i]);
    float e = (t < Nn) ? expf(v - bm) : 0.0f;
    float ssum = e;
    for (int off = 32; off; off >>= 1) ssum += __shfl_xor(ssum, off, 64);
    __syncthreads();
    if ((t & 63) == 0) red[t >> 6] = ssum;
    __syncthreads();
    float tot = 0.f;
    for (int i = 0; i < 8; ++i) tot += red[i];
    bvs[t] = e / tot;
    __syncthreads();
    const float* ncb = nc + (size_t)b * Nn * ENC;
    float acc = 0.f;
    for (int n = 0; n < Nn; ++n) acc = fmaf(bvs[n], ncb[(size_t)n * ENC + t], acc);
    q2n[b * ENC + t] = acc;
}

// ---------------------------------------------------------------------------
// raw[row] = b2 + sum_h tanh(sum_z part[z][row][h] + b1[h]) * W2[h]
__global__ __launch_bounds__(256) void final_reduce_k(const float* __restrict__ part,
                                                      const float* __restrict__ b1p,
                                                      const float* __restrict__ W2p,
                                                      const float* __restrict__ b2p,
                                                      float* __restrict__ raw) {
    constexpr int M = Bn * Nn;
    int wave = threadIdx.x >> 6, lane = threadIdx.x & 63;
    int row = blockIdx.x * 4 + wave;
    if (row >= M) return;
    float v0 = 0.f, v1 = 0.f;
#pragma unroll
    for (int s = 0; s < 4; ++s) {
        const float* pr = part + ((size_t)s * M + row) * 128;
        v0 += pr[lane];
        v1 += pr[lane + 64];
    }
    float p = tanhf(v0 + b1p[lane]) * W2p[lane] + tanhf(v1 + b1p[lane + 64]) * W2p[lane + 64];
    for (int off = 32; off; off >>= 1) p += __shfl_xor(p, off, 64);
    if (lane == 0) raw[row] = p + b2p[0];
}

// ---------------------------------------------------------------------------
__global__ __launch_bounds__(256) void predmax_k(const int* __restrict__ mask,
                                                 const float* __restrict__ raw,
                                                 float* __restrict__ out) {
    int idx = blockIdx.x * 4 + (threadIdx.x >> 6);
    int lane = threadIdx.x & 63;
    if (idx >= Bn * NCn) return;
    int b = idx / NCn, c = idx - b * NCn;
    const int* mrow = mask + ((size_t)b * NCn + c) * Nn;
    const float* rrow = raw + (size_t)b * Nn;
    float mx = -INFINITY;
    for (int n = lane; n < Nn; n += 64) {
        float v = mrow[n] ? rrow[n] : 0.0f;
        if (v == 0.0f) v = -1.0e6f;
        mx = fmaxf(mx, v);
    }
    for (int off = 32; off; off >>= 1) mx = fmaxf(mx, __shfl_xor(mx, off, 64));
    if (lane == 0) out[idx] = mx;
}

}  // namespace

extern "C" void kernel_launch(void* const* d_in, const int* in_sizes, int n_in,
                              void* d_out, int out_size, void* d_ws, size_t ws_size,
                              hipStream_t stream) {
    const float* nodes_glove  = (const float*)d_in[0];
    const float* query_glove  = (const float*)d_in[1];
    const float* adj          = (const float*)d_in[2];
    const int*   nodes_length = (const int*)d_in[3];
    const int*   maskp        = (const int*)d_in[4];
    const float* Wn = (const float*)d_in[5];
    const float* bn = (const float*)d_in[6];
    const float* Wq = (const float*)d_in[7];
    const float* bq = (const float*)d_in[8];
    const float* Wh = (const float*)d_in[9];
    const float* bh = (const float*)d_in[10];
    const float* Wc = (const float*)d_in[11];
    const float* bc = (const float*)d_in[12];
    const float* wa = (const float*)d_in[13];
    const float* W1 = (const float*)d_in[14];
    const float* b1 = (const float*)d_in[15];
    const float* W2 = (const float*)d_in[16];
    const float* b2 = (const float*)d_in[17];
    float* out = (float*)d_out;

    float* ws = (float*)d_ws;
    size_t off = 0;
    auto alloc = [&](size_t n) { float* p = ws + off; off += n; return p; };
    constexpr size_t ME  = (size_t)Bn * Nn * ENC;       // 2,048,000 fp32 elems
    constexpr size_t MEH = ME / 2;
    float* nc   = alloc(ME);
    float* Asum = alloc(ME);       // fp32 adjacency; then n2q; then part buf
    float* pa   = alloc(ME);       // fp32 partial att logits (lh @ Wc_lo)
    unsigned short* lh0 = (unsigned short*)alloc(MEH);
    unsigned short* lh1 = (unsigned short*)alloc(MEH);
    unsigned short* upd = (unsigned short*)alloc(MEH);
    unsigned short* hm  = (unsigned short*)alloc(MEH);
    unsigned short* gbf = (unsigned short*)alloc(ME * 2);   // [4000][2048] bf16
    float* qc   = alloc((size_t)Bn * Qn * ENC);
    float* rowmax = alloc(Bn * Nn);
    float* q2n    = alloc(Bn * ENC);
    float* raw    = alloc(Bn * Nn);
    unsigned short* WnT  = (unsigned short*)alloc((size_t)ENC * 320 / 2);
    unsigned short* WqT  = (unsigned short*)alloc((size_t)ENC * 320 / 2);
    unsigned short* WhcT = (unsigned short*)alloc((size_t)1024 * 512 / 2);
    unsigned short* WcHiT = (unsigned short*)alloc((size_t)512 * 512 / 2);
    unsigned short* W1T  = (unsigned short*)alloc((size_t)128 * 2048 / 2);
    unsigned int* bar = (unsigned int*)alloc(64);  // R19 barrier state (256 B)
    alloc(16384 - 64);  // tail pad
    float* n2q  = Asum;            // phase 2
    float* part = Asum;            // phase 3 (after gbf consumed n2q)

    constexpr int M = Bn * Nn;  // 4000

    // R19: zero barrier state each launch (workspace is poisoned between
    // iterations; memsetAsync is graph-capture-safe — harness uses it too).
    hipMemsetAsync(bar, 0, 256, stream);

    // Fused prep: adjacency sum (z=1) + all weight transposes (z=0).
    prep_k<<<dim3(2048, 1, 2), 256, 0, stream>>>(adj, Asum, Wn, Wq, Wh, Wc, W1,
                                                 WnT, WqT, WhcT, WcHiT, W1T);

    // R18/R19: mega kernel (gemm_in + 3 hops + sim) with software barriers.
    mega_k<<<dim3(512), dim3(256), 0, stream>>>(
        nodes_glove, query_glove, WnT, WqT, bn, bq, nodes_length,
        nc, lh0, qc, Asum, WhcT, WcHiT, bh, bc,
        hm, upd, pa, lh1, wa, n2q, rowmax, bar);

    bvec_q2n_k<<<dim3(Bn), 512, 0, stream>>>(rowmax, nc, q2n);
    gbf_k<<<dim3(M), 256, 0, stream>>>(nc, n2q, q2n, gbf);       // consumes n2q
    gemm_final_k<<<dim3((M + 63) / 64, 2, 4), 256, 0, stream>>>(gbf, W1T, part);
    final_reduce_k<<<dim3((M + 3) / 4), 256, 0, stream>>>(part, b1, W2, b2, raw);
    predmax_k<<<dim3((Bn * NCn + 3) / 4), 256, 0, stream>>>(maskp, raw, out);
}

// Round 5
// 317.646 us; speedup vs baseline: 5.3175x; 5.3175x over previous
//
#include <hip/hip_runtime.h>
#include <hip/hip_bf16.h>
#include <math.h>
#include <stdint.h>

namespace {

constexpr int Bn  = 8;
constexpr int Nn  = 500;
constexpr int Qn  = 25;
constexpr int ENC = 512;
constexpr int DIN = 300;
constexpr int NCn = 70;
constexpr int NETn = 3;

typedef __attribute__((ext_vector_type(8))) short bf16x8_t;
typedef __attribute__((ext_vector_type(4))) float f32x4_t;

__device__ __forceinline__ unsigned short f2bf(float f) {
    union { __hip_bfloat16 b; unsigned short u; } r;
    r.b = __float2bfloat16(f);
    return r.u;
}
__device__ __forceinline__ bf16x8_t cvt8(float4 f0, float4 f1) {
    union { bf16x8_t v; __hip_bfloat162 b[4]; } r;
    r.b[0] = __float22bfloat162_rn(make_float2(f0.x, f0.y));
    r.b[1] = __float22bfloat162_rn(make_float2(f0.z, f0.w));
    r.b[2] = __float22bfloat162_rn(make_float2(f1.x, f1.y));
    r.b[3] = __float22bfloat162_rn(make_float2(f1.z, f1.w));
    return r.v;
}
__device__ __forceinline__ float bf2f(unsigned short h) {
    unsigned int u = ((unsigned int)h) << 16;
    return __builtin_bit_cast(float, u);
}
__device__ __forceinline__ float sigmoidf_(float x) { return 1.0f / (1.0f + expf(-x)); }

// R20: async global->LDS, 16B per lane.  HW dest = wave-uniform base +
// lane*16B; our layout (thread t -> As + t*8 shorts) is exactly that per
// wave.  Source address is per-lane (swizzle pre-applied on k-offset).
typedef __attribute__((address_space(1))) const unsigned int g_u32;
typedef __attribute__((address_space(3))) unsigned int l_u32;
__device__ __forceinline__ void gld16(const void* g, void* l) {
    __builtin_amdgcn_global_load_lds((g_u32*)g, (l_u32*)l, 16, 0, 0);
}

// ---------------------------------------------------------------------------
// Fused prep: z=1 -> Asum (2 adjacency rows per block); z=0 -> all weight
// transposes (tile decoded from blockIdx.x).
__global__ __launch_bounds__(256) void prep_k(
    const float* __restrict__ adj, float* __restrict__ Asum,
    const float* __restrict__ Wn, const float* __restrict__ Wq,
    const float* __restrict__ Wh, const float* __restrict__ Wc,
    const float* __restrict__ W1,
    unsigned short* __restrict__ WnT, unsigned short* __restrict__ WqT,
    unsigned short* __restrict__ WhcT, unsigned short* __restrict__ WcHiT,
    unsigned short* __restrict__ W1T) {
    if (blockIdx.z == 1) {
        int bi = blockIdx.x * 2 + (threadIdx.x >> 7);
        if (bi >= Bn * Nn) return;
        int b = bi / Nn, i = bi - b * Nn;
        int j = (threadIdx.x & 127) * 4;
        float4 s = make_float4(0.f, 0.f, 0.f, 0.f);
        if (j < Nn) {
#pragma unroll
            for (int e = 0; e < NETn; ++e) {
                const float* p = adj + (((size_t)(b * NETn + e) * Nn) + i) * Nn + j;
                float4 v = *(const float4*)p;
                s.x += v.x; s.y += v.y; s.z += v.z; s.w += v.w;
            }
        }
        *(float4*)(Asum + ((size_t)bi) * 512 + j) = s;
        return;
    }
    __shared__ float tile[32][33];
    int x = blockIdx.x;
    const float* in; unsigned short* out; int K, N, Kpad, tx, ty;
    if (x < 160)       { in = Wn; out = WnT; K = DIN; N = ENC; Kpad = 320;
                         tx = x & 15; ty = x >> 4; }
    else if (x < 320)  { int l = x - 160; in = Wq; out = WqT; K = DIN; N = ENC;
                         Kpad = 320; tx = l & 15; ty = l >> 4; }
    else if (x < 576)  { int l = x - 320; in = Wh; out = WhcT; K = 512; N = ENC;
                         Kpad = 512; tx = l & 15; ty = l >> 4; }
    else if (x < 832)  { int l = x - 576; in = Wc + (size_t)512 * ENC;
                         out = WhcT + (size_t)512 * 512; K = 512; N = ENC;
                         Kpad = 512; tx = l & 15; ty = l >> 4; }
    else if (x < 1088) { int l = x - 832; in = Wc; out = WcHiT; K = 512; N = ENC;
                         Kpad = 512; tx = l & 15; ty = l >> 4; }
    else if (x < 1344) { int l = x - 1088; in = W1; out = W1T; K = 2048; N = 128;
                         Kpad = 2048; tx = l & 3; ty = l >> 2; }
    else return;
    int n0 = tx * 32, k0 = ty * 32;
    int ltx = threadIdx.x & 31, lty = threadIdx.x >> 5;
#pragma unroll
    for (int r = 0; r < 4; ++r) {
        int k = k0 + lty * 4 + r;
        int n = n0 + ltx;
        tile[lty * 4 + r][ltx] = (k < K && n < N) ? in[(size_t)k * N + n] : 0.0f;
    }
    __syncthreads();
#pragma unroll
    for (int r = 0; r < 4; ++r) {
        int n = n0 + lty * 4 + r;
        int k = k0 + ltx;
        if (n < N && k < Kpad) out[(size_t)n * Kpad + k] = f2bf(tile[ltx][lty * 4 + r]);
    }
}

// ---------------------------------------------------------------------------
// MFMA core, BK=64: 64x64 tile, 4 waves, double-buffered LDS, one barrier
// per 64-k step.
// R20: AMODE 1 stages A and B via global_load_lds (direct-to-LDS DMA, no
// VGPR round trip).  AMODE 0 (fp32 A, needs cvt) keeps reg staging for A,
// uses global_load_lds for B.  OOB A rows are clamped to Mlim-1 (finite
// garbage; MFMA rows are independent and epilogue masks row >= Mlim).
// NOTE (R15): keep LDS at 32KB/block -> 4 blocks/CU.
template <int AMODE>
__device__ __forceinline__ void mfma_core(
    const float* __restrict__ A,
    const unsigned short* __restrict__ Abf,
    int lda, int Klim,
    const unsigned short* __restrict__ Bt, int ldb,
    int m0, int n0, int K, int Mlim,
    unsigned short* As, unsigned short* Bts, f32x4_t acc[2][2]) {
    const int t = threadIdx.x;
    const int lane = t & 63;
    const int w = t >> 6;
    const int sm = t >> 2;
    const int sp = t & 3;
    const int sq = sp ^ ((sm >> 1) & 3);
    const int arow = m0 + sm;
    const bool rowok = arow < Mlim;
    const int arowc = rowok ? arow : (Mlim - 1);
    const int wm = (w & 1) * 32, wn = (w >> 1) * 32;
    const int quad = lane >> 4, cidx = lane & 15;
    const int am0 = wm + cidx, am1 = wm + 16 + cidx;
    const int an0 = wn + cidx, an1 = wn + 16 + cidx;
    const int apo0 = am0 * 32 + (quad ^ ((am0 >> 1) & 3)) * 8;
    const int apo1 = am1 * 32 + (quad ^ ((am1 >> 1) & 3)) * 8;
    const int bpo0 = an0 * 32 + (quad ^ ((an0 >> 1) & 3)) * 8;
    const int bpo1 = an1 * 32 + (quad ^ ((an1 >> 1) & 3)) * 8;
    const int wbase = w * 512;  // shorts; wave-uniform LDS base (lane*16B HW)

    const unsigned short* abase = (AMODE == 1) ? Abf + (size_t)arowc * lda : nullptr;
    const unsigned short* bbase = Bt + (size_t)(n0 + sm) * ldb;
    const int ko0 = sq * 8, ko1 = 32 + sq * 8;

    float4 raf0, raf1, raf2, raf3;  // AMODE 0 A reg staging
    auto stageA0 = [&](int kg, float4& f0, float4& f1) {
        f0 = make_float4(0.f, 0.f, 0.f, 0.f);
        f1 = make_float4(0.f, 0.f, 0.f, 0.f);
        if (rowok) {
            const float* src = A + (size_t)arow * lda + kg;
            if (kg + 8 <= Klim) {
                f0 = *(const float4*)src;
                f1 = *(const float4*)(src + 4);
            } else if (kg + 4 <= Klim) {
                f0 = *(const float4*)src;
            }
        }
    };

    const int ktot = K >> 6;
    // Prologue: fill buffer 0.
    if (AMODE == 1) {
        gld16(abase + ko0, As + wbase);
        gld16(abase + ko1, As + 2048 + wbase);
    } else {
        stageA0(ko0, raf0, raf1);
        stageA0(ko1, raf2, raf3);
        *(bf16x8_t*)(As + t * 8) = cvt8(raf0, raf1);
        *(bf16x8_t*)(As + 2048 + t * 8) = cvt8(raf2, raf3);
    }
    gld16(bbase + ko0, Bts + wbase);
    gld16(bbase + ko1, Bts + 2048 + wbase);

    for (int kt = 0; kt < ktot; ++kt) {
        __syncthreads();  // drains vmcnt (gld16) + lgkm (ds_write) + barrier
        const int cur = (kt & 1) * 4096;
        const int nxt = cur ^ 4096;
        const bool more = (kt + 1) < ktot;
        const int kn = (kt + 1) << 6;
        if (more) {
            if (AMODE == 1) {
                gld16(abase + kn + ko0, As + nxt + wbase);
                gld16(abase + kn + ko1, As + nxt + 2048 + wbase);
            } else {
                stageA0(kn + ko0, raf0, raf1);
                stageA0(kn + ko1, raf2, raf3);
            }
            gld16(bbase + kn + ko0, Bts + nxt + wbase);
            gld16(bbase + kn + ko1, Bts + nxt + 2048 + wbase);
        }
        {
            bf16x8_t a0 = *(const bf16x8_t*)(As + cur + apo0);
            bf16x8_t a1 = *(const bf16x8_t*)(As + cur + apo1);
            bf16x8_t b0 = *(const bf16x8_t*)(Bts + cur + bpo0);
            bf16x8_t b1 = *(const bf16x8_t*)(Bts + cur + bpo1);
            acc[0][0] = __builtin_amdgcn_mfma_f32_16x16x32_bf16(a0, b0, acc[0][0], 0, 0, 0);
            acc[0][1] = __builtin_amdgcn_mfma_f32_16x16x32_bf16(a0, b1, acc[0][1], 0, 0, 0);
            acc[1][0] = __builtin_amdgcn_mfma_f32_16x16x32_bf16(a1, b0, acc[1][0], 0, 0, 0);
            acc[1][1] = __builtin_amdgcn_mfma_f32_16x16x32_bf16(a1, b1, acc[1][1], 0, 0, 0);
        }
        {
            bf16x8_t a0 = *(const bf16x8_t*)(As + cur + 2048 + apo0);
            bf16x8_t a1 = *(const bf16x8_t*)(As + cur + 2048 + apo1);
            bf16x8_t b0 = *(const bf16x8_t*)(Bts + cur + 2048 + bpo0);
            bf16x8_t b1 = *(const bf16x8_t*)(Bts + cur + 2048 + bpo1);
            acc[0][0] = __builtin_amdgcn_mfma_f32_16x16x32_bf16(a0, b0, acc[0][0], 0, 0, 0);
            acc[0][1] = __builtin_amdgcn_mfma_f32_16x16x32_bf16(a0, b1, acc[0][1], 0, 0, 0);
            acc[1][0] = __builtin_amdgcn_mfma_f32_16x16x32_bf16(a1, b0, acc[1][0], 0, 0, 0);
            acc[1][1] = __builtin_amdgcn_mfma_f32_16x16x32_bf16(a1, b1, acc[1][1], 0, 0, 0);
        }
        if (more && AMODE == 0) {
            *(bf16x8_t*)(As + nxt + t * 8) = cvt8(raf0, raf1);
            *(bf16x8_t*)(As + nxt + 2048 + t * 8) = cvt8(raf2, raf3);
        }
    }
}

#define EPI_SETUP                                         \
    int t = threadIdx.x, lane = t & 63, w = t >> 6;       \
    int wm = (w & 1) * 32, wn = (w >> 1) * 32;            \
    int quad = lane >> 4, cidx = lane & 15;               \
    (void)wm; (void)wn; (void)quad; (void)cidx;

// R17: tile fully dead iff single-batch tile with i0 >= lens[b].
__device__ __forceinline__ bool tile_dead(int m0, const int* __restrict__ lens) {
    int bA = m0 / Nn;
    int lastRow = m0 + 63;
    if (lastRow >= Bn * Nn) lastRow = Bn * Nn - 1;
    int bB = lastRow / Nn;
    return (bA == bB) && ((m0 - bA * Nn) >= lens[bA]);
}

// ---------------------------------------------------------------------------
// Fused input GEMMs, grid (67, 8):
//   x <  63: nc = tanh(ng@Wn+bn) fp32; lh0 = bf16(nc * rowmask)
//   x >= 63: qc = qg@Wq + bq
__global__ __launch_bounds__(256) void gemm_in_k(const float* __restrict__ ng,
                                                 const float* __restrict__ qg,
                                                 const unsigned short* __restrict__ WnT,
                                                 const unsigned short* __restrict__ WqT,
                                                 const float* __restrict__ bn,
                                                 const float* __restrict__ bq,
                                                 const int* __restrict__ lens,
                                                 float* __restrict__ nc,
                                                 unsigned short* __restrict__ lh0,
                                                 float* __restrict__ qc) {
    __shared__ __align__(16) unsigned short As[8192], Bts[8192];
    f32x4_t z = {0.f, 0.f, 0.f, 0.f};
    f32x4_t acc[2][2] = {{z, z}, {z, z}};
    const bool isq = blockIdx.x >= 63;
    int m0 = (isq ? (blockIdx.x - 63) : blockIdx.x) * 64;
    int n0 = blockIdx.y * 64;
    const float* A = isq ? qg : ng;
    const unsigned short* Bt = isq ? WqT : WnT;
    const int Mlim = isq ? Bn * Qn : Bn * Nn;
    mfma_core<0>(A, nullptr, DIN, DIN, Bt, 320, m0, n0, 320, Mlim, As, Bts, acc);
    EPI_SETUP
#pragma unroll
    for (int nj = 0; nj < 2; ++nj) {
        int col = n0 + wn + nj * 16 + cidx;
        float bias = isq ? bq[col] : bn[col];
#pragma unroll
        for (int mi = 0; mi < 2; ++mi) {
#pragma unroll
            for (int r = 0; r < 4; ++r) {
                int row = m0 + wm + mi * 16 + quad * 4 + r;
                if (row < Mlim) {
                    float v = acc[mi][nj][r] + bias;
                    if (isq) {
                        qc[(size_t)row * ENC + col] = v;
                    } else {
                        float tv = tanhf(v);
                        int b = row / Nn, i = row - b * Nn;
                        float rm = (i < lens[b]) ? 1.0f : 0.0f;
                        nc[(size_t)row * ENC + col] = tv;
                        lh0[(size_t)row * ENC + col] = f2bf(tv * rm);
                    }
                }
            }
        }
    }
}

// ---------------------------------------------------------------------------
// Wide hop GEMM: lh @ [Wh | Wc_lo]  (N=1024, K=512).
// cols 0..511  -> hm = bf16((x + bh)*rm);  cols 512..1023 -> pa = x (fp32).
// R17: dead tiles write hm=0, skip GEMM; pa unwritten there (never read —
// gemm_att_k skips the same x-tiles).
__global__ __launch_bounds__(256) void gemm_hmw_k(const unsigned short* __restrict__ lh,
                                                  const unsigned short* __restrict__ WhcT,
                                                  const float* __restrict__ bh,
                                                  const int* __restrict__ lens,
                                                  unsigned short* __restrict__ hm,
                                                  float* __restrict__ pa) {
    int m0 = blockIdx.x * 64, n0 = blockIdx.y * 64;   // n0 in [0,1024)
    if (tile_dead(m0, lens)) {
        if (n0 < 512) {
            int tt = threadIdx.x;
            int row = m0 + (tt >> 2);
            int cseg = (tt & 3) * 16;
            if (row < Bn * Nn) {
                bf16x8_t zz = {0, 0, 0, 0, 0, 0, 0, 0};
                *(bf16x8_t*)(hm + (size_t)row * ENC + n0 + cseg) = zz;
                *(bf16x8_t*)(hm + (size_t)row * ENC + n0 + cseg + 8) = zz;
            }
        }
        return;
    }
    __shared__ __align__(16) unsigned short As[8192], Bts[8192];
    f32x4_t z = {0.f, 0.f, 0.f, 0.f};
    f32x4_t acc[2][2] = {{z, z}, {z, z}};
    mfma_core<1>(nullptr, lh, ENC, ENC, WhcT, 512, m0, n0, ENC,
                 Bn * Nn, As, Bts, acc);
    EPI_SETUP
#pragma unroll
    for (int nj = 0; nj < 2; ++nj) {
        int col = n0 + wn + nj * 16 + cidx;
        bool ishm = col < 512;
        float bias = ishm ? bh[col] : 0.0f;
#pragma unroll
        for (int mi = 0; mi < 2; ++mi) {
#pragma unroll
            for (int r = 0; r < 4; ++r) {
                int row = m0 + wm + mi * 16 + quad * 4 + r;
                if (row < Bn * Nn) {
                    int b = row / Nn, i = row - b * Nn;
                    float rm = (i < lens[b]) ? 1.0f : 0.0f;
                    float v = acc[mi][nj][r];
                    if (ishm) {
                        hm[(size_t)row * ENC + col] = f2bf((v + bias) * rm);
                    } else {
                        pa[(size_t)row * ENC + (col - 512)] = v;
                    }
                }
            }
        }
    }
}

// ---------------------------------------------------------------------------
// Sparse aggregation: upd[b,i,:] = hm[b,i,:] + sum_j Asum[b,i,j]*hm[b,j,:].
// R17: masked rows write zeros and skip the gather.
__global__ __launch_bounds__(256) void upd_sparse_k(const float* __restrict__ Asum,
                                                    const unsigned short* __restrict__ hm,
                                                    const int* __restrict__ lens,
                                                    unsigned short* __restrict__ upd) {
    int wv = threadIdx.x >> 6, lane = threadIdx.x & 63;
    int row = blockIdx.x * 4 + wv;
    int b = row / Nn, i = row - b * Nn;
    int d0 = lane * 8;
    if (i >= lens[b]) {
        bf16x8_t zz = {0, 0, 0, 0, 0, 0, 0, 0};
        *(bf16x8_t*)(upd + (size_t)row * ENC + d0) = zz;
        return;
    }
    const float* arow = Asum + (size_t)row * 512;
    const unsigned short* hmb = hm + (size_t)b * Nn * ENC;

    float acc[8];
    {
        bf16x8_t h = *(const bf16x8_t*)(hmb + (size_t)i * ENC + d0);
#pragma unroll
        for (int j = 0; j < 8; ++j) acc[j] = bf2f((unsigned short)h[j]);
    }
#pragma unroll
    for (int c = 0; c < 8; ++c) {
        int j = c * 64 + lane;
        float val = (j < Nn) ? arow[j] : 0.0f;
        unsigned long long mask = __ballot(val != 0.0f);
        while (mask) {
            int b0 = __ffsll((unsigned long long)mask) - 1;
            mask &= mask - 1;
            int b1 = -1;
            if (mask) { b1 = __ffsll((unsigned long long)mask) - 1; mask &= mask - 1; }
            float v0 = __shfl(val, b0, 64);
            bf16x8_t x = *(const bf16x8_t*)(hmb + (size_t)(c * 64 + b0) * ENC + d0);
            float v1 = 0.0f;
            bf16x8_t y = {0, 0, 0, 0, 0, 0, 0, 0};
            if (b1 >= 0) {
                v1 = __shfl(val, b1, 64);
                y = *(const bf16x8_t*)(hmb + (size_t)(c * 64 + b1) * ENC + d0);
            }
#pragma unroll
            for (int k = 0; k < 8; ++k)
                acc[k] += v0 * bf2f((unsigned short)x[k]) + v1 * bf2f((unsigned short)y[k]);
        }
    }
    float4 o0 = make_float4(acc[0], acc[1], acc[2], acc[3]);
    float4 o1 = make_float4(acc[4], acc[5], acc[6], acc[7]);
    *(bf16x8_t*)(upd + (size_t)row * ENC + d0) = cvt8(o0, o1);
}

// ---------------------------------------------------------------------------
// att = sigmoid(upd@Wc_hi + pa + bc)*rm; lh_out = bf16(att*tanh(upd)+(1-att)*lh)
// R17: dead tiles write lh_out = 0 and skip the GEMM.
__global__ __launch_bounds__(256) void gemm_att_k(const unsigned short* __restrict__ upd,
                                                  const unsigned short* __restrict__ lh,
                                                  const unsigned short* __restrict__ WcHiT,
                                                  const float* __restrict__ pa,
                                                  const float* __restrict__ bc,
                                                  const int* __restrict__ lens,
                                                  unsigned short* __restrict__ lh_out) {
    int m0 = blockIdx.x * 64, n0 = blockIdx.y * 64;
    if (tile_dead(m0, lens)) {
        int tt = threadIdx.x;
        int row = m0 + (tt >> 2);
        int cseg = (tt & 3) * 16;
        if (row < Bn * Nn) {
            bf16x8_t zz = {0, 0, 0, 0, 0, 0, 0, 0};
            *(bf16x8_t*)(lh_out + (size_t)row * ENC + n0 + cseg) = zz;
            *(bf16x8_t*)(lh_out + (size_t)row * ENC + n0 + cseg + 8) = zz;
        }
        return;
    }
    __shared__ __align__(16) unsigned short As[8192], Bts[8192];
    f32x4_t z = {0.f, 0.f, 0.f, 0.f};
    f32x4_t acc[2][2] = {{z, z}, {z, z}};
    mfma_core<1>(nullptr, upd, ENC, ENC, WcHiT, 512, m0, n0, ENC,
                 Bn * Nn, As, Bts, acc);
    EPI_SETUP
#pragma unroll
    for (int nj = 0; nj < 2; ++nj) {
        int col = n0 + wn + nj * 16 + cidx;
        float bias = bc[col];
#pragma unroll
        for (int mi = 0; mi < 2; ++mi) {
#pragma unroll
            for (int r = 0; r < 4; ++r) {
                int row = m0 + wm + mi * 16 + quad * 4 + r;
                if (row < Bn * Nn) {
                    int b = row / Nn, i = row - b * Nn;
                    float rm = (i < lens[b]) ? 1.0f : 0.0f;
                    size_t off = (size_t)row * ENC + col;
                    float a = sigmoidf_(acc[mi][nj][r] + pa[off] + bias) * rm;
                    float u = bf2f(upd[off]);
                    float l = bf2f(lh[off]);
                    lh_out[off] = f2bf(a * tanhf(u) + (1.0f - a) * l);
                }
            }
        }
    }
}

// ---------------------------------------------------------------------------
// Materialize g = [nc | n2q | nc*n2q | nc*q2n] as bf16 [4000][2048].
__global__ __launch_bounds__(256) void gbf_k(const float* __restrict__ nc,
                                             const float* __restrict__ n2q,
                                             const float* __restrict__ q2n,
                                             unsigned short* __restrict__ gbf) {
    int row = blockIdx.x;
    int b = row / Nn;
    int t = threadIdx.x;
    int seg = t >> 6;
    int d = (t & 63) * 8;
    size_t off = (size_t)row * ENC + d;
    float4 a0, a1;
    if (seg == 0) {
        a0 = *(const float4*)(nc + off); a1 = *(const float4*)(nc + off + 4);
    } else if (seg == 1) {
        a0 = *(const float4*)(n2q + off); a1 = *(const float4*)(n2q + off + 4);
    } else if (seg == 2) {
        float4 x0 = *(const float4*)(nc + off), x1 = *(const float4*)(nc + off + 4);
        float4 y0 = *(const float4*)(n2q + off), y1 = *(const float4*)(n2q + off + 4);
        a0 = make_float4(x0.x * y0.x, x0.y * y0.y, x0.z * y0.z, x0.w * y0.w);
        a1 = make_float4(x1.x * y1.x, x1.y * y1.y, x1.z * y1.z, x1.w * y1.w);
    } else {
        float4 x0 = *(const float4*)(nc + off), x1 = *(const float4*)(nc + off + 4);
        const float* qp = q2n + (size_t)b * ENC + d;
        float4 y0 = *(const float4*)qp, y1 = *(const float4*)(qp + 4);
        a0 = make_float4(x0.x * y0.x, x0.y * y0.y, x0.z * y0.z, x0.w * y0.w);
        a1 = make_float4(x1.x * y1.x, x1.y * y1.y, x1.z * y1.z, x1.w * y1.w);
    }
    *(bf16x8_t*)(gbf + (size_t)row * 2048 + seg * 512 + d) = cvt8(a0, a1);
}

// ---------------------------------------------------------------------------
// g @ W1 split-K partials via MFMA; z = K-slice in [0,4) (512 wide).
__global__ __launch_bounds__(256) void gemm_final_k(const unsigned short* __restrict__ gbf,
                                                    const unsigned short* __restrict__ W1T,
                                                    float* __restrict__ part) {
    __shared__ __align__(16) unsigned short As[8192], Bts[8192];
    f32x4_t z4 = {0.f, 0.f, 0.f, 0.f};
    f32x4_t acc[2][2] = {{z4, z4}, {z4, z4}};
    int zz = blockIdx.z;
    int m0 = blockIdx.x * 64, n0 = blockIdx.y * 64;
    mfma_core<1>(nullptr, gbf + zz * 512, 2048, 1 << 30,
                 W1T + zz * 512, 2048, m0, n0, 512, Bn * Nn, As, Bts, acc);
    EPI_SETUP
    constexpr int M = Bn * Nn;
#pragma unroll
    for (int nj = 0; nj < 2; ++nj) {
        int col = n0 + wn + nj * 16 + cidx;
#pragma unroll
        for (int mi = 0; mi < 2; ++mi) {
#pragma unroll
            for (int r = 0; r < 4; ++r) {
                int row = m0 + wm + mi * 16 + quad * 4 + r;
                if (row < M) part[((size_t)zz * M + row) * 128 + col] = acc[mi][nj][r];
            }
        }
    }
}

// ---------------------------------------------------------------------------
// Fused sim -> softmax(q) -> nodes2query + rowmax.  One wave per n-row.
// R17: masked rows take the light path (sim row = qdot only).
__global__ __launch_bounds__(256) void sim_fused_k(const unsigned short* __restrict__ lh,
                                                   const float* __restrict__ qc,
                                                   const float* __restrict__ wa,
                                                   const int* __restrict__ lens,
                                                   float* __restrict__ n2q,
                                                   float* __restrict__ rowmax) {
    __shared__ float qcs[Qn * ENC];
    __shared__ float qdot[32];
    int b = blockIdx.x;
    int t = threadIdx.x;
    const float* qcb = qc + (size_t)b * Qn * ENC;
    for (int i = t * 4; i < Qn * ENC; i += 1024) *(float4*)&qcs[i] = *(const float4*)&qcb[i];
    __syncthreads();
    {
        int q = t >> 3, j = t & 7;
        if (q < Qn) {
            float s = 0.f;
            for (int k = 0; k < 64; ++k) {
                int d = j + 8 * k;
                s += qcs[q * ENC + d] * wa[ENC + d];
            }
            s += __shfl_xor(s, 1, 64);
            s += __shfl_xor(s, 2, 64);
            s += __shfl_xor(s, 4, 64);
            if (j == 0) qdot[q] = s;
        }
    }
    __syncthreads();

    int wv = t >> 6, lane = t & 63;
    int n = blockIdx.y * 4 + wv;
    int dA = lane * 4;
    int dB = 256 + lane * 4;
    const bool valid = n < lens[b];

    float s_[Qn];
    if (valid) {
        const unsigned short* lrow = lh + ((size_t)b * Nn + n) * ENC;
        ushort4 ua = *(const ushort4*)(lrow + dA);
        ushort4 ub = *(const ushort4*)(lrow + dB);
        float lv[8] = {bf2f(ua.x), bf2f(ua.y), bf2f(ua.z), bf2f(ua.w),
                       bf2f(ub.x), bf2f(ub.y), bf2f(ub.z), bf2f(ub.w)};
        float ndp = 0.f;
        float lvs[8];
#pragma unroll
        for (int j = 0; j < 4; ++j) {
            ndp += lv[j] * wa[dA + j];
            lvs[j] = lv[j] * wa[2 * ENC + dA + j];
            ndp += lv[4 + j] * wa[dB + j];
            lvs[4 + j] = lv[4 + j] * wa[2 * ENC + dB + j];
        }
#pragma unroll
        for (int off = 32; off; off >>= 1) ndp += __shfl_xor(ndp, off, 64);

#pragma unroll
        for (int q = 0; q < Qn; ++q) {
            float4 qa = *(const float4*)(qcs + q * ENC + dA);
            float4 qb = *(const float4*)(qcs + q * ENC + dB);
            s_[q] = lvs[0] * qa.x + lvs[1] * qa.y + lvs[2] * qa.z + lvs[3] * qa.w +
                    lvs[4] * qb.x + lvs[5] * qb.y + lvs[6] * qb.z + lvs[7] * qb.w;
        }
#pragma unroll
        for (int q = 0; q < Qn; ++q) {
#pragma unroll
            for (int off = 32; off; off >>= 1) s_[q] += __shfl_xor(s_[q], off, 64);
        }
#pragma unroll
        for (int q = 0; q < Qn; ++q) s_[q] += ndp + qdot[q];
    } else {
#pragma unroll
        for (int q = 0; q < Qn; ++q) s_[q] = qdot[q];
    }

    float mx = -INFINITY;
#pragma unroll
    for (int q = 0; q < Qn; ++q) mx = fmaxf(mx, s_[q]);
    float sum = 0.f;
#pragma unroll
    for (int q = 0; q < Qn; ++q) { s_[q] = expf(s_[q] - mx); sum += s_[q]; }
    float inv = 1.0f / sum;
    float o[8] = {};
#pragma unroll
    for (int q = 0; q < Qn; ++q) {
        float4 qa = *(const float4*)(qcs + q * ENC + dA);
        float4 qb = *(const float4*)(qcs + q * ENC + dB);
        float p = s_[q] * inv;
        o[0] += p * qa.x; o[1] += p * qa.y; o[2] += p * qa.z; o[3] += p * qa.w;
        o[4] += p * qb.x; o[5] += p * qb.y; o[6] += p * qb.z; o[7] += p * qb.w;
    }
    float* orow = n2q + ((size_t)b * Nn + n) * ENC;
    *(float4*)(orow + dA) = make_float4(o[0], o[1], o[2], o[3]);
    *(float4*)(orow + dB) = make_float4(o[4], o[5], o[6], o[7]);
    if (lane == 0) rowmax[b * Nn + n] = mx;
}

// ---------------------------------------------------------------------------
// Fused bvec (softmax over rowmax) + q2n (bvec-weighted sum of nc).
__global__ __launch_bounds__(512) void bvec_q2n_k(const float* __restrict__ rowmax,
                                                  const float* __restrict__ nc,
                                                  float* __restrict__ q2n) {
    __shared__ float red[8];
    __shared__ float bvs[512];
    int b = blockIdx.x, t = threadIdx.x;
    float v = (t < Nn) ? rowmax[b * Nn + t] : -INFINITY;
    float m = v;
    for (int off = 32; off; off >>= 1) m = fmaxf(m, __shfl_xor(m, off, 64));
    if ((t & 63) == 0) red[t >> 6] = m;
    __syncthreads();
    float bm = red[0];
    for (int i = 1; i < 8; ++i) bm = fmaxf(bm, red[i]);
    float e = (t < Nn) ? expf(v - bm) : 0.0f;
    float ssum = e;
    for (int off = 32; off; off >>= 1) ssum += __shfl_xor(ssum, off, 64);
    __syncthreads();
    if ((t & 63) == 0) red[t >> 6] = ssum;
    __syncthreads();
    float tot = 0.f;
    for (int i = 0; i < 8; ++i) tot += red[i];
    bvs[t] = e / tot;
    __syncthreads();
    const float* ncb = nc + (size_t)b * Nn * ENC;
    float acc = 0.f;
    for (int n = 0; n < Nn; ++n) acc = fmaf(bvs[n], ncb[(size_t)n * ENC + t], acc);
    q2n[b * ENC + t] = acc;
}

// ---------------------------------------------------------------------------
// raw[row] = b2 + sum_h tanh(sum_z part[z][row][h] + b1[h]) * W2[h]
__global__ __launch_bounds__(256) void final_reduce_k(const float* __restrict__ part,
                                                      const float* __restrict__ b1p,
                                                      const float* __restrict__ W2p,
                                                      const float* __restrict__ b2p,
                                                      float* __restrict__ raw) {
    constexpr int M = Bn * Nn;
    int wave = threadIdx.x >> 6, lane = threadIdx.x & 63;
    int row = blockIdx.x * 4 + wave;
    if (row >= M) return;
    float v0 = 0.f, v1 = 0.f;
#pragma unroll
    for (int s = 0; s < 4; ++s) {
        const float* pr = part + ((size_t)s * M + row) * 128;
        v0 += pr[lane];
        v1 += pr[lane + 64];
    }
    float p = tanhf(v0 + b1p[lane]) * W2p[lane] + tanhf(v1 + b1p[lane + 64]) * W2p[lane + 64];
    for (int off = 32; off; off >>= 1) p += __shfl_xor(p, off, 64);
    if (lane == 0) raw[row] = p + b2p[0];
}

// ---------------------------------------------------------------------------
__global__ __launch_bounds__(256) void predmax_k(const int* __restrict__ mask,
                                                 const float* __restrict__ raw,
                                                 float* __restrict__ out) {
    int idx = blockIdx.x * 4 + (threadIdx.x >> 6);
    int lane = threadIdx.x & 63;
    if (idx >= Bn * NCn) return;
    int b = idx / NCn, c = idx - b * NCn;
    const int* mrow = mask + ((size_t)b * NCn + c) * Nn;
    const float* rrow = raw + (size_t)b * Nn;
    float mx = -INFINITY;
    for (int n = lane; n < Nn; n += 64) {
        float v = mrow[n] ? rrow[n] : 0.0f;
        if (v == 0.0f) v = -1.0e6f;
        mx = fmaxf(mx, v);
    }
    for (int off = 32; off; off >>= 1) mx = fmaxf(mx, __shfl_xor(mx, off, 64));
    if (lane == 0) out[idx] = mx;
}

}  // namespace

extern "C" void kernel_launch(void* const* d_in, const int* in_sizes, int n_in,
                              void* d_out, int out_size, void* d_ws, size_t ws_size,
                              hipStream_t stream) {
    const float* nodes_glove  = (const float*)d_in[0];
    const float* query_glove  = (const float*)d_in[1];
    const float* adj          = (const float*)d_in[2];
    const int*   nodes_length = (const int*)d_in[3];
    const int*   maskp        = (const int*)d_in[4];
    const float* Wn = (const float*)d_in[5];
    const float* bn = (const float*)d_in[6];
    const float* Wq = (const float*)d_in[7];
    const float* bq = (const float*)d_in[8];
    const float* Wh = (const float*)d_in[9];
    const float* bh = (const float*)d_in[10];
    const float* Wc = (const float*)d_in[11];
    const float* bc = (const float*)d_in[12];
    const float* wa = (const float*)d_in[13];
    const float* W1 = (const float*)d_in[14];
    const float* b1 = (const float*)d_in[15];
    const float* W2 = (const float*)d_in[16];
    const float* b2 = (const float*)d_in[17];
    float* out = (float*)d_out;

    float* ws = (float*)d_ws;
    size_t off = 0;
    auto alloc = [&](size_t n) { float* p = ws + off; off += n; return p; };
    constexpr size_t ME  = (size_t)Bn * Nn * ENC;       // 2,048,000 fp32 elems
    constexpr size_t MEH = ME / 2;
    float* nc   = alloc(ME);
    float* Asum = alloc(ME);       // fp32 adjacency; then n2q; then part buf
    float* pa   = alloc(ME);       // fp32 partial att logits (lh @ Wc_lo)
    unsigned short* lh0 = (unsigned short*)alloc(MEH);
    unsigned short* lh1 = (unsigned short*)alloc(MEH);
    unsigned short* upd = (unsigned short*)alloc(MEH);
    unsigned short* hm  = (unsigned short*)alloc(MEH);
    unsigned short* gbf = (unsigned short*)alloc(ME * 2);   // [4000][2048] bf16
    float* qc   = alloc((size_t)Bn * Qn * ENC);
    float* rowmax = alloc(Bn * Nn);
    float* q2n    = alloc(Bn * ENC);
    float* raw    = alloc(Bn * Nn);
    unsigned short* WnT  = (unsigned short*)alloc((size_t)ENC * 320 / 2);
    unsigned short* WqT  = (unsigned short*)alloc((size_t)ENC * 320 / 2);
    unsigned short* WhcT = (unsigned short*)alloc((size_t)1024 * 512 / 2);
    unsigned short* WcHiT = (unsigned short*)alloc((size_t)512 * 512 / 2);
    unsigned short* W1T  = (unsigned short*)alloc((size_t)128 * 2048 / 2);
    alloc(16384);  // tail pad
    float* n2q  = Asum;            // phase 2
    float* part = Asum;            // phase 3 (after gbf consumed n2q)

    constexpr int M = Bn * Nn;  // 4000

    // Fused prep: adjacency sum (z=1) + all weight transposes (z=0).
    prep_k<<<dim3(2048, 1, 2), 256, 0, stream>>>(adj, Asum, Wn, Wq, Wh, Wc, W1,
                                                 WnT, WqT, WhcT, WcHiT, W1T);

    // Fused input GEMMs (nc: x<63, qc: x>=63).
    gemm_in_k<<<dim3(67, 8), 256, 0, stream>>>(nodes_glove, query_glove, WnT, WqT,
                                               bn, bq, nodes_length, nc, lh0, qc);

    // 3 hops; cur starts at lh0, after 3 swaps cur==lh1.
    unsigned short* cur = lh0;
    unsigned short* nxt = lh1;
    for (int h = 0; h < 3; ++h) {
        gemm_hmw_k<<<dim3((M + 63) / 64, 16), 256, 0, stream>>>(cur, WhcT, bh,
                                                                nodes_length, hm, pa);
        upd_sparse_k<<<dim3(M / 4), 256, 0, stream>>>(Asum, hm, nodes_length, upd);
        gemm_att_k<<<dim3((M + 63) / 64, 8), 256, 0, stream>>>(upd, cur, WcHiT, pa,
                                                               bc, nodes_length, nxt);
        unsigned short* tmp = cur; cur = nxt; nxt = tmp;
    }
    // cur == lh1 == final last_hop.

    sim_fused_k<<<dim3(Bn, 125), 256, 0, stream>>>(cur, qc, wa, nodes_length, n2q, rowmax);
    bvec_q2n_k<<<dim3(Bn), 512, 0, stream>>>(rowmax, nc, q2n);
    gbf_k<<<dim3(M), 256, 0, stream>>>(nc, n2q, q2n, gbf);       // consumes n2q
    gemm_final_k<<<dim3((M + 63) / 64, 2, 4), 256, 0, stream>>>(gbf, W1T, part);
    final_reduce_k<<<dim3((M + 3) / 4), 256, 0, stream>>>(part, b1, W2, b2, raw);
    predmax_k<<<dim3((Bn * NCn + 3) / 4), 256, 0, stream>>>(maskp, raw, out);
}

// Round 6
// 309.149 us; speedup vs baseline: 5.4637x; 1.0275x over previous
//
#include <hip/hip_runtime.h>
#include <hip/hip_bf16.h>
#include <math.h>
#include <stdint.h>

namespace {

constexpr int Bn  = 8;
constexpr int Nn  = 500;
constexpr int Qn  = 25;
constexpr int ENC = 512;
constexpr int DIN = 300;
constexpr int NCn = 70;
constexpr int NETn = 3;

typedef __attribute__((ext_vector_type(8))) short bf16x8_t;
typedef __attribute__((ext_vector_type(4))) float f32x4_t;

__device__ __forceinline__ unsigned short f2bf(float f) {
    union { __hip_bfloat16 b; unsigned short u; } r;
    r.b = __float2bfloat16(f);
    return r.u;
}
__device__ __forceinline__ bf16x8_t cvt8(float4 f0, float4 f1) {
    union { bf16x8_t v; __hip_bfloat162 b[4]; } r;
    r.b[0] = __float22bfloat162_rn(make_float2(f0.x, f0.y));
    r.b[1] = __float22bfloat162_rn(make_float2(f0.z, f0.w));
    r.b[2] = __float22bfloat162_rn(make_float2(f1.x, f1.y));
    r.b[3] = __float22bfloat162_rn(make_float2(f1.z, f1.w));
    return r.v;
}
__device__ __forceinline__ float bf2f(unsigned short h) {
    unsigned int u = ((unsigned int)h) << 16;
    return __builtin_bit_cast(float, u);
}
__device__ __forceinline__ float sigmoidf_(float x) { return 1.0f / (1.0f + expf(-x)); }

// R20: async global->LDS, 16B per lane (dest = wave-uniform base + lane*16B).
typedef __attribute__((address_space(1))) const unsigned int g_u32;
typedef __attribute__((address_space(3))) unsigned int l_u32;
__device__ __forceinline__ void gld16(const void* g, void* l) {
    __builtin_amdgcn_global_load_lds((g_u32*)g, (l_u32*)l, 16, 0, 0);
}

// ---------------------------------------------------------------------------
// Fused prep: z=1 -> Asum; z=0 -> weight transposes.
// WhcT is now [1536][512] B^T: rows 0-511 Wh^T, 512-1023 Wc_lo^T,
// 1024-1535 Whc2^T (filled later by gemm_in_k).
__global__ __launch_bounds__(256) void prep_k(
    const float* __restrict__ adj, float* __restrict__ Asum,
    const float* __restrict__ Wn, const float* __restrict__ Wq,
    const float* __restrict__ Wh, const float* __restrict__ Wc,
    const float* __restrict__ W1,
    unsigned short* __restrict__ WnT, unsigned short* __restrict__ WqT,
    unsigned short* __restrict__ WhcT, unsigned short* __restrict__ WcHiT,
    unsigned short* __restrict__ W1T) {
    if (blockIdx.z == 1) {
        int bi = blockIdx.x * 2 + (threadIdx.x >> 7);
        if (bi >= Bn * Nn) return;
        int b = bi / Nn, i = bi - b * Nn;
        int j = (threadIdx.x & 127) * 4;
        float4 s = make_float4(0.f, 0.f, 0.f, 0.f);
        if (j < Nn) {
#pragma unroll
            for (int e = 0; e < NETn; ++e) {
                const float* p = adj + (((size_t)(b * NETn + e) * Nn) + i) * Nn + j;
                float4 v = *(const float4*)p;
                s.x += v.x; s.y += v.y; s.z += v.z; s.w += v.w;
            }
        }
        *(float4*)(Asum + ((size_t)bi) * 512 + j) = s;
        return;
    }
    __shared__ float tile[32][33];
    int x = blockIdx.x;
    const float* in; unsigned short* out; int K, N, Kpad, tx, ty;
    if (x < 160)       { in = Wn; out = WnT; K = DIN; N = ENC; Kpad = 320;
                         tx = x & 15; ty = x >> 4; }
    else if (x < 320)  { int l = x - 160; in = Wq; out = WqT; K = DIN; N = ENC;
                         Kpad = 320; tx = l & 15; ty = l >> 4; }
    else if (x < 576)  { int l = x - 320; in = Wh; out = WhcT; K = 512; N = ENC;
                         Kpad = 512; tx = l & 15; ty = l >> 4; }
    else if (x < 832)  { int l = x - 576; in = Wc + (size_t)512 * ENC;
                         out = WhcT + (size_t)512 * 512; K = 512; N = ENC;
                         Kpad = 512; tx = l & 15; ty = l >> 4; }
    else if (x < 1088) { int l = x - 832; in = Wc; out = WcHiT; K = 512; N = ENC;
                         Kpad = 512; tx = l & 15; ty = l >> 4; }
    else if (x < 1344) { int l = x - 1088; in = W1; out = W1T; K = 2048; N = 128;
                         Kpad = 2048; tx = l & 3; ty = l >> 2; }
    else return;
    int n0 = tx * 32, k0 = ty * 32;
    int ltx = threadIdx.x & 31, lty = threadIdx.x >> 5;
#pragma unroll
    for (int r = 0; r < 4; ++r) {
        int k = k0 + lty * 4 + r;
        int n = n0 + ltx;
        tile[lty * 4 + r][ltx] = (k < K && n < N) ? in[(size_t)k * N + n] : 0.0f;
    }
    __syncthreads();
#pragma unroll
    for (int r = 0; r < 4; ++r) {
        int n = n0 + lty * 4 + r;
        int k = k0 + ltx;
        if (n < N && k < Kpad) out[(size_t)n * Kpad + k] = f2bf(tile[ltx][lty * 4 + r]);
    }
}

// ---------------------------------------------------------------------------
// MFMA core, BK=64: 64x64 tile, 4 waves, double-buffered LDS.
// AMODE 0: A fp32 (Klim clamp).  AMODE 1: A bf16 (gld16 direct).
// AMODE 2 (R21): A = fp32 product stage — a2mode 0: A only; 1: A*A2 same-row;
// 2: A * A2[b-row broadcast].  B always bf16 B^T via gld16.
template <int AMODE>
__device__ __forceinline__ void mfma_core(
    const float* __restrict__ A, const float* __restrict__ A2, int a2mode,
    const unsigned short* __restrict__ Abf,
    int lda, int Klim,
    const unsigned short* __restrict__ Bt, int ldb,
    int m0, int n0, int K, int Mlim,
    unsigned short* As, unsigned short* Bts, f32x4_t acc[2][2]) {
    const int t = threadIdx.x;
    const int lane = t & 63;
    const int w = t >> 6;
    const int sm = t >> 2;
    const int sp = t & 3;
    const int sq = sp ^ ((sm >> 1) & 3);
    const int arow = m0 + sm;
    const bool rowok = arow < Mlim;
    const int arowc = rowok ? arow : (Mlim - 1);
    const int wm = (w & 1) * 32, wn = (w >> 1) * 32;
    const int quad = lane >> 4, cidx = lane & 15;
    const int am0 = wm + cidx, am1 = wm + 16 + cidx;
    const int an0 = wn + cidx, an1 = wn + 16 + cidx;
    const int apo0 = am0 * 32 + (quad ^ ((am0 >> 1) & 3)) * 8;
    const int apo1 = am1 * 32 + (quad ^ ((am1 >> 1) & 3)) * 8;
    const int bpo0 = an0 * 32 + (quad ^ ((an0 >> 1) & 3)) * 8;
    const int bpo1 = an1 * 32 + (quad ^ ((an1 >> 1) & 3)) * 8;
    const int wbase = w * 512;  // shorts; wave-uniform LDS base

    const unsigned short* abase = (AMODE == 1) ? Abf + (size_t)arowc * lda : nullptr;
    const unsigned short* bbase = Bt + (size_t)(n0 + sm) * ldb;
    const int ko0 = sq * 8, ko1 = 32 + sq * 8;
    const float* a2row = nullptr;
    if (AMODE == 2 && A2 != nullptr)
        a2row = (a2mode == 2) ? A2 + (size_t)(arowc / Nn) * ENC
                              : A2 + (size_t)arowc * lda;

    float4 raf0, raf1, raf2, raf3;  // fp32 A reg staging
    auto stageAF = [&](int kg, float4& f0, float4& f1) {
        f0 = make_float4(0.f, 0.f, 0.f, 0.f);
        f1 = make_float4(0.f, 0.f, 0.f, 0.f);
        if (rowok) {
            const float* src = A + (size_t)arow * lda + kg;
            if (AMODE == 2) {
                f0 = *(const float4*)src;
                f1 = *(const float4*)(src + 4);
                if (a2mode) {
                    float4 g0 = *(const float4*)(a2row + kg);
                    float4 g1 = *(const float4*)(a2row + kg + 4);
                    f0 = make_float4(f0.x * g0.x, f0.y * g0.y, f0.z * g0.z, f0.w * g0.w);
                    f1 = make_float4(f1.x * g1.x, f1.y * g1.y, f1.z * g1.z, f1.w * g1.w);
                }
            } else {
                if (kg + 8 <= Klim) {
                    f0 = *(const float4*)src;
                    f1 = *(const float4*)(src + 4);
                } else if (kg + 4 <= Klim) {
                    f0 = *(const float4*)src;
                }
            }
        }
    };

    const int ktot = K >> 6;
    if (AMODE == 1) {
        gld16(abase + ko0, As + wbase);
        gld16(abase + ko1, As + 2048 + wbase);
    } else {
        stageAF(ko0, raf0, raf1);
        stageAF(ko1, raf2, raf3);
        *(bf16x8_t*)(As + t * 8) = cvt8(raf0, raf1);
        *(bf16x8_t*)(As + 2048 + t * 8) = cvt8(raf2, raf3);
    }
    gld16(bbase + ko0, Bts + wbase);
    gld16(bbase + ko1, Bts + 2048 + wbase);

    for (int kt = 0; kt < ktot; ++kt) {
        __syncthreads();
        const int cur = (kt & 1) * 4096;
        const int nxt = cur ^ 4096;
        const bool more = (kt + 1) < ktot;
        const int kn = (kt + 1) << 6;
        if (more) {
            if (AMODE == 1) {
                gld16(abase + kn + ko0, As + nxt + wbase);
                gld16(abase + kn + ko1, As + nxt + 2048 + wbase);
            } else {
                stageAF(kn + ko0, raf0, raf1);
                stageAF(kn + ko1, raf2, raf3);
            }
            gld16(bbase + kn + ko0, Bts + nxt + wbase);
            gld16(bbase + kn + ko1, Bts + nxt + 2048 + wbase);
        }
        {
            bf16x8_t a0 = *(const bf16x8_t*)(As + cur + apo0);
            bf16x8_t a1 = *(const bf16x8_t*)(As + cur + apo1);
            bf16x8_t b0 = *(const bf16x8_t*)(Bts + cur + bpo0);
            bf16x8_t b1 = *(const bf16x8_t*)(Bts + cur + bpo1);
            acc[0][0] = __builtin_amdgcn_mfma_f32_16x16x32_bf16(a0, b0, acc[0][0], 0, 0, 0);
            acc[0][1] = __builtin_amdgcn_mfma_f32_16x16x32_bf16(a0, b1, acc[0][1], 0, 0, 0);
            acc[1][0] = __builtin_amdgcn_mfma_f32_16x16x32_bf16(a1, b0, acc[1][0], 0, 0, 0);
            acc[1][1] = __builtin_amdgcn_mfma_f32_16x16x32_bf16(a1, b1, acc[1][1], 0, 0, 0);
        }
        {
            bf16x8_t a0 = *(const bf16x8_t*)(As + cur + 2048 + apo0);
            bf16x8_t a1 = *(const bf16x8_t*)(As + cur + 2048 + apo1);
            bf16x8_t b0 = *(const bf16x8_t*)(Bts + cur + 2048 + bpo0);
            bf16x8_t b1 = *(const bf16x8_t*)(Bts + cur + 2048 + bpo1);
            acc[0][0] = __builtin_amdgcn_mfma_f32_16x16x32_bf16(a0, b0, acc[0][0], 0, 0, 0);
            acc[0][1] = __builtin_amdgcn_mfma_f32_16x16x32_bf16(a0, b1, acc[0][1], 0, 0, 0);
            acc[1][0] = __builtin_amdgcn_mfma_f32_16x16x32_bf16(a1, b0, acc[1][0], 0, 0, 0);
            acc[1][1] = __builtin_amdgcn_mfma_f32_16x16x32_bf16(a1, b1, acc[1][1], 0, 0, 0);
        }
        if (more && AMODE != 1) {
            *(bf16x8_t*)(As + nxt + t * 8) = cvt8(raf0, raf1);
            *(bf16x8_t*)(As + nxt + 2048 + t * 8) = cvt8(raf2, raf3);
        }
    }
}

#define EPI_SETUP                                         \
    int t = threadIdx.x, lane = t & 63, w = t >> 6;       \
    int wm = (w & 1) * 32, wn = (w >> 1) * 32;            \
    int quad = lane >> 4, cidx = lane & 15;               \
    (void)t; (void)lane; (void)wm; (void)wn; (void)quad; (void)cidx;

// R17: tile fully dead iff single-batch tile with i0 >= lens[b].
__device__ __forceinline__ bool tile_dead(int m0, const int* __restrict__ lens) {
    int bA = m0 / Nn;
    int lastRow = m0 + 63;
    if (lastRow >= Bn * Nn) lastRow = Bn * Nn - 1;
    int bB = lastRow / Nn;
    return (bA == bB) && ((m0 - bA * Nn) >= lens[bA]);
}

// ---------------------------------------------------------------------------
// R21 fused input dispatch, 601 blocks 1D:
//   idx <  504: nc = tanh(ng@Wn+bn), lh0    (63 x-tiles x 8 y)
//   idx <  536: qc = qg@Wq + bq             (4 x 8)
//   idx <  600: Whc2 = Wh @ Wc_hi  -> WhcT rows 1024-1535 (B^T, bf16)
//   idx == 600: bhc2 = bh @ Wc_hi  (512 fp32)
__global__ __launch_bounds__(256) void gemm_in_k(
    const float* __restrict__ ng, const float* __restrict__ qg,
    const float* __restrict__ Wh, const float* __restrict__ Wc,
    const float* __restrict__ bh,
    const unsigned short* __restrict__ WnT, const unsigned short* __restrict__ WqT,
    const unsigned short* __restrict__ WcHiT,
    const float* __restrict__ bn, const float* __restrict__ bq,
    const int* __restrict__ lens,
    float* __restrict__ nc, unsigned short* __restrict__ lh0,
    float* __restrict__ qc,
    unsigned short* __restrict__ WhcT, float* __restrict__ bhc2) {
    int idx = blockIdx.x;
    if (idx >= 600) {  // bhc2
        int n = threadIdx.x;
        float s0 = 0.f, s1 = 0.f;
        for (int k = 0; k < 512; ++k) {
            float bv = bh[k];
            s0 = fmaf(bv, Wc[(size_t)k * 512 + n], s0);
            s1 = fmaf(bv, Wc[(size_t)k * 512 + n + 256], s1);
        }
        bhc2[n] = s0; bhc2[n + 256] = s1;
        return;
    }
    __shared__ __align__(16) unsigned short As[8192], Bts[8192];
    f32x4_t z = {0.f, 0.f, 0.f, 0.f};
    f32x4_t acc[2][2] = {{z, z}, {z, z}};
    if (idx >= 536) {  // Whc2 tile (8x8)
        int l = idx - 536;
        int m0 = (l >> 3) * 64, n0 = (l & 7) * 64;
        mfma_core<0>(Wh, nullptr, 0, nullptr, 512, 512, WcHiT, 512,
                     m0, n0, 512, 512, As, Bts, acc);
        EPI_SETUP
#pragma unroll
        for (int nj = 0; nj < 2; ++nj) {
            int col = n0 + wn + nj * 16 + cidx;
#pragma unroll
            for (int mi = 0; mi < 2; ++mi) {
#pragma unroll
                for (int r = 0; r < 4; ++r) {
                    int row = m0 + wm + mi * 16 + quad * 4 + r;
                    WhcT[(size_t)(1024 + col) * 512 + row] = f2bf(acc[mi][nj][r]);
                }
            }
        }
        return;
    }
    const bool isq = idx >= 504;
    int xt = isq ? (idx - 504) % 4 : idx % 63;
    int yt = isq ? (idx - 504) / 4 : idx / 63;
    int m0 = xt * 64, n0 = yt * 64;
    const float* A = isq ? qg : ng;
    const unsigned short* Bt = isq ? WqT : WnT;
    const int Mlim = isq ? Bn * Qn : Bn * Nn;
    mfma_core<0>(A, nullptr, 0, nullptr, DIN, DIN, Bt, 320,
                 m0, n0, 320, Mlim, As, Bts, acc);
    EPI_SETUP
#pragma unroll
    for (int nj = 0; nj < 2; ++nj) {
        int col = n0 + wn + nj * 16 + cidx;
        float bias = isq ? bq[col] : bn[col];
#pragma unroll
        for (int mi = 0; mi < 2; ++mi) {
#pragma unroll
            for (int r = 0; r < 4; ++r) {
                int row = m0 + wm + mi * 16 + quad * 4 + r;
                if (row < Mlim) {
                    float v = acc[mi][nj][r] + bias;
                    if (isq) {
                        qc[(size_t)row * ENC + col] = v;
                    } else {
                        float tv = tanhf(v);
                        int b = row / Nn, i = row - b * Nn;
                        float rm = (i < lens[b]) ? 1.0f : 0.0f;
                        nc[(size_t)row * ENC + col] = tv;
                        lh0[(size_t)row * ENC + col] = f2bf(tv * rm);
                    }
                }
            }
        }
    }
}

// ---------------------------------------------------------------------------
// R21 hop K1: lh @ [Wh | Wc_lo | Whc2]  (N=1536, K=512), grid (63, 24).
// cols 0-511    -> hm = bf16((v+bh)*rm)
// cols 512-1023 -> pa = v (fp32)
// cols 1024-1535-> X  = (v + bhc2)*rm (fp32)   [X = hm @ Wc_hi algebraically]
// Dead tiles: hm=0, X=0, skip GEMM (pa unread for dead rows).
__global__ __launch_bounds__(256) void gemm_hop_k(
    const unsigned short* __restrict__ lh, const unsigned short* __restrict__ WhcT,
    const float* __restrict__ bh, const float* __restrict__ bhc2,
    const int* __restrict__ lens,
    unsigned short* __restrict__ hm, float* __restrict__ pa,
    float* __restrict__ Xb) {
    int m0 = blockIdx.x * 64, n0 = blockIdx.y * 64;   // n0 in [0,1536)
    if (tile_dead(m0, lens)) {
        int tt = threadIdx.x;
        int row = m0 + (tt >> 2);
        if (row < Bn * Nn) {
            if (n0 < 512) {
                int cseg = (tt & 3) * 16;
                bf16x8_t zz = {0, 0, 0, 0, 0, 0, 0, 0};
                *(bf16x8_t*)(hm + (size_t)row * ENC + n0 + cseg) = zz;
                *(bf16x8_t*)(hm + (size_t)row * ENC + n0 + cseg + 8) = zz;
            } else if (n0 >= 1024) {
                int c0 = (n0 - 1024) + (tt & 3) * 16;
                float4 z4 = make_float4(0.f, 0.f, 0.f, 0.f);
                float* xp = Xb + (size_t)row * 512 + c0;
                *(float4*)(xp) = z4; *(float4*)(xp + 4) = z4;
                *(float4*)(xp + 8) = z4; *(float4*)(xp + 12) = z4;
            }
        }
        return;
    }
    __shared__ __align__(16) unsigned short As[8192], Bts[8192];
    f32x4_t z = {0.f, 0.f, 0.f, 0.f};
    f32x4_t acc[2][2] = {{z, z}, {z, z}};
    mfma_core<1>(nullptr, nullptr, 0, lh, ENC, ENC, WhcT, 512, m0, n0, ENC,
                 Bn * Nn, As, Bts, acc);
    EPI_SETUP
#pragma unroll
    for (int nj = 0; nj < 2; ++nj) {
        int col = n0 + wn + nj * 16 + cidx;
#pragma unroll
        for (int mi = 0; mi < 2; ++mi) {
#pragma unroll
            for (int r = 0; r < 4; ++r) {
                int row = m0 + wm + mi * 16 + quad * 4 + r;
                if (row < Bn * Nn) {
                    int b = row / Nn, i = row - b * Nn;
                    float rm = (i < lens[b]) ? 1.0f : 0.0f;
                    float v = acc[mi][nj][r];
                    if (col < 512) {
                        hm[(size_t)row * ENC + col] = f2bf((v + bh[col]) * rm);
                    } else if (col < 1024) {
                        pa[(size_t)row * ENC + (col - 512)] = v;
                    } else {
                        Xb[(size_t)row * 512 + (col - 1024)] =
                            (v + bhc2[col - 1024]) * rm;
                    }
                }
            }
        }
    }
}

// ---------------------------------------------------------------------------
// R21 hop K2: dual sparse gather + attention + hop update (fused, no upd buf).
// For valid row i: upd = hm[i] + A.hm;  Xa = X[i] + A.X;
// att = sigmoid(Xa + pa + bc); lh_out = att*tanh(upd) + (1-att)*lh.
__global__ __launch_bounds__(256) void upd_att_k(
    const float* __restrict__ Asum, const unsigned short* __restrict__ hm,
    const float* __restrict__ Xb, const float* __restrict__ pa,
    const float* __restrict__ bc, const int* __restrict__ lens,
    const unsigned short* __restrict__ lh, unsigned short* __restrict__ lh_out) {
    int wv = threadIdx.x >> 6, lane = threadIdx.x & 63;
    int row = blockIdx.x * 4 + wv;
    int b = row / Nn, i = row - b * Nn;
    int d0 = lane * 8;
    if (i >= lens[b]) {
        bf16x8_t zz = {0, 0, 0, 0, 0, 0, 0, 0};
        *(bf16x8_t*)(lh_out + (size_t)row * ENC + d0) = zz;
        return;
    }
    const float* arow = Asum + (size_t)row * 512;
    const unsigned short* hmb = hm + (size_t)b * Nn * ENC;
    const float* Xbb = Xb + (size_t)b * Nn * 512;

    float ua[8], xa[8];
    {
        bf16x8_t h = *(const bf16x8_t*)(hmb + (size_t)i * ENC + d0);
#pragma unroll
        for (int j = 0; j < 8; ++j) ua[j] = bf2f((unsigned short)h[j]);
        const float* xp = Xbb + (size_t)i * 512 + d0;
        float4 x0 = *(const float4*)xp, x1 = *(const float4*)(xp + 4);
        xa[0] = x0.x; xa[1] = x0.y; xa[2] = x0.z; xa[3] = x0.w;
        xa[4] = x1.x; xa[5] = x1.y; xa[6] = x1.z; xa[7] = x1.w;
    }
#pragma unroll
    for (int c = 0; c < 8; ++c) {
        int j = c * 64 + lane;
        float val = (j < Nn) ? arow[j] : 0.0f;
        unsigned long long mask = __ballot(val != 0.0f);
        while (mask) {
            int b0 = __ffsll((unsigned long long)mask) - 1;
            mask &= mask - 1;
            int b1 = -1;
            if (mask) { b1 = __ffsll((unsigned long long)mask) - 1; mask &= mask - 1; }
            float v0 = __shfl(val, b0, 64);
            bf16x8_t x = *(const bf16x8_t*)(hmb + (size_t)(c * 64 + b0) * ENC + d0);
            const float* xq0 = Xbb + (size_t)(c * 64 + b0) * 512 + d0;
            float4 xv0a = *(const float4*)xq0, xv0b = *(const float4*)(xq0 + 4);
            float v1 = 0.0f;
            bf16x8_t y = {0, 0, 0, 0, 0, 0, 0, 0};
            float4 xv1a = make_float4(0.f, 0.f, 0.f, 0.f);
            float4 xv1b = make_float4(0.f, 0.f, 0.f, 0.f);
            if (b1 >= 0) {
                v1 = __shfl(val, b1, 64);
                y = *(const bf16x8_t*)(hmb + (size_t)(c * 64 + b1) * ENC + d0);
                const float* xq1 = Xbb + (size_t)(c * 64 + b1) * 512 + d0;
                xv1a = *(const float4*)xq1; xv1b = *(const float4*)(xq1 + 4);
            }
#pragma unroll
            for (int k = 0; k < 8; ++k)
                ua[k] += v0 * bf2f((unsigned short)x[k]) + v1 * bf2f((unsigned short)y[k]);
            xa[0] += v0 * xv0a.x + v1 * xv1a.x;
            xa[1] += v0 * xv0a.y + v1 * xv1a.y;
            xa[2] += v0 * xv0a.z + v1 * xv1a.z;
            xa[3] += v0 * xv0a.w + v1 * xv1a.w;
            xa[4] += v0 * xv0b.x + v1 * xv1b.x;
            xa[5] += v0 * xv0b.y + v1 * xv1b.y;
            xa[6] += v0 * xv0b.z + v1 * xv1b.z;
            xa[7] += v0 * xv0b.w + v1 * xv1b.w;
        }
    }
    // Epilogue: att + hop update.
    const float* pp = pa + (size_t)row * ENC + d0;
    float4 p0 = *(const float4*)pp, p1 = *(const float4*)(pp + 4);
    float4 c0 = *(const float4*)(bc + d0), c1 = *(const float4*)(bc + d0 + 4);
    float pk[8] = {p0.x, p0.y, p0.z, p0.w, p1.x, p1.y, p1.z, p1.w};
    float ck[8] = {c0.x, c0.y, c0.z, c0.w, c1.x, c1.y, c1.z, c1.w};
    bf16x8_t lr = *(const bf16x8_t*)(lh + (size_t)row * ENC + d0);
    float o[8];
#pragma unroll
    for (int k = 0; k < 8; ++k) {
        float a = sigmoidf_(xa[k] + pk[k] + ck[k]);   // rm=1 (valid row)
        float l = bf2f((unsigned short)lr[k]);
        o[k] = a * tanhf(ua[k]) + (1.0f - a) * l;
    }
    float4 o0 = make_float4(o[0], o[1], o[2], o[3]);
    float4 o1 = make_float4(o[4], o[5], o[6], o[7]);
    *(bf16x8_t*)(lh_out + (size_t)row * ENC + d0) = cvt8(o0, o1);
}

// ---------------------------------------------------------------------------
// R21 gemm_final: g @ W1 split-K with on-the-fly g staging (gbf eliminated).
// z = K-slice: 0: nc; 1: n2q; 2: nc*n2q; 3: nc*q2n[b].
__global__ __launch_bounds__(256) void gemm_final_k(
    const float* __restrict__ nc, const float* n2q,
    const float* __restrict__ q2n,
    const unsigned short* __restrict__ W1T, float* __restrict__ part) {
    __shared__ __align__(16) unsigned short As[8192], Bts[8192];
    f32x4_t z4 = {0.f, 0.f, 0.f, 0.f};
    f32x4_t acc[2][2] = {{z4, z4}, {z4, z4}};
    int zz = blockIdx.z;
    int m0 = blockIdx.x * 64, n0 = blockIdx.y * 64;
    const float* Ap  = (zz == 1) ? n2q : nc;
    const float* A2p = (zz == 2) ? n2q : ((zz == 3) ? q2n : nullptr);
    int a2m = (zz == 2) ? 1 : ((zz == 3) ? 2 : 0);
    mfma_core<2>(Ap, A2p, a2m, nullptr, ENC, 512, W1T + zz * 512, 2048,
                 m0, n0, 512, Bn * Nn, As, Bts, acc);
    EPI_SETUP
    constexpr int M = Bn * Nn;
#pragma unroll
    for (int nj = 0; nj < 2; ++nj) {
        int col = n0 + wn + nj * 16 + cidx;
#pragma unroll
        for (int mi = 0; mi < 2; ++mi) {
#pragma unroll
            for (int r = 0; r < 4; ++r) {
                int row = m0 + wm + mi * 16 + quad * 4 + r;
                if (row < M) part[((size_t)zz * M + row) * 128 + col] = acc[mi][nj][r];
            }
        }
    }
}

// ---------------------------------------------------------------------------
// Fused sim -> softmax(q) -> nodes2query + rowmax.  One wave per n-row.
__global__ __launch_bounds__(256) void sim_fused_k(const unsigned short* __restrict__ lh,
                                                   const float* __restrict__ qc,
                                                   const float* __restrict__ wa,
                                                   const int* __restrict__ lens,
                                                   float* __restrict__ n2q,
                                                   float* __restrict__ rowmax) {
    __shared__ float qcs[Qn * ENC];
    __shared__ float qdot[32];
    int b = blockIdx.x;
    int t = threadIdx.x;
    const float* qcb = qc + (size_t)b * Qn * ENC;
    for (int i = t * 4; i < Qn * ENC; i += 1024) *(float4*)&qcs[i] = *(const float4*)&qcb[i];
    __syncthreads();
    {
        int q = t >> 3, j = t & 7;
        if (q < Qn) {
            float s = 0.f;
            for (int k = 0; k < 64; ++k) {
                int d = j + 8 * k;
                s += qcs[q * ENC + d] * wa[ENC + d];
            }
            s += __shfl_xor(s, 1, 64);
            s += __shfl_xor(s, 2, 64);
            s += __shfl_xor(s, 4, 64);
            if (j == 0) qdot[q] = s;
        }
    }
    __syncthreads();

    int wv = t >> 6, lane = t & 63;
    int n = blockIdx.y * 4 + wv;
    int dA = lane * 4;
    int dB = 256 + lane * 4;
    const bool valid = n < lens[b];

    float s_[Qn];
    if (valid) {
        const unsigned short* lrow = lh + ((size_t)b * Nn + n) * ENC;
        ushort4 ua = *(const ushort4*)(lrow + dA);
        ushort4 ub = *(const ushort4*)(lrow + dB);
        float lv[8] = {bf2f(ua.x), bf2f(ua.y), bf2f(ua.z), bf2f(ua.w),
                       bf2f(ub.x), bf2f(ub.y), bf2f(ub.z), bf2f(ub.w)};
        float ndp = 0.f;
        float lvs[8];
#pragma unroll
        for (int j = 0; j < 4; ++j) {
            ndp += lv[j] * wa[dA + j];
            lvs[j] = lv[j] * wa[2 * ENC + dA + j];
            ndp += lv[4 + j] * wa[dB + j];
            lvs[4 + j] = lv[4 + j] * wa[2 * ENC + dB + j];
        }
#pragma unroll
        for (int off = 32; off; off >>= 1) ndp += __shfl_xor(ndp, off, 64);

#pragma unroll
        for (int q = 0; q < Qn; ++q) {
            float4 qa = *(const float4*)(qcs + q * ENC + dA);
            float4 qb = *(const float4*)(qcs + q * ENC + dB);
            s_[q] = lvs[0] * qa.x + lvs[1] * qa.y + lvs[2] * qa.z + lvs[3] * qa.w +
                    lvs[4] * qb.x + lvs[5] * qb.y + lvs[6] * qb.z + lvs[7] * qb.w;
        }
#pragma unroll
        for (int q = 0; q < Qn; ++q) {
#pragma unroll
            for (int off = 32; off; off >>= 1) s_[q] += __shfl_xor(s_[q], off, 64);
        }
#pragma unroll
        for (int q = 0; q < Qn; ++q) s_[q] += ndp + qdot[q];
    } else {
#pragma unroll
        for (int q = 0; q < Qn; ++q) s_[q] = qdot[q];
    }

    float mx = -INFINITY;
#pragma unroll
    for (int q = 0; q < Qn; ++q) mx = fmaxf(mx, s_[q]);
    float sum = 0.f;
#pragma unroll
    for (int q = 0; q < Qn; ++q) { s_[q] = expf(s_[q] - mx); sum += s_[q]; }
    float inv = 1.0f / sum;
    float o[8] = {};
#pragma unroll
    for (int q = 0; q < Qn; ++q) {
        float4 qa = *(const float4*)(qcs + q * ENC + dA);
        float4 qb = *(const float4*)(qcs + q * ENC + dB);
        float p = s_[q] * inv;
        o[0] += p * qa.x; o[1] += p * qa.y; o[2] += p * qa.z; o[3] += p * qa.w;
        o[4] += p * qb.x; o[5] += p * qb.y; o[6] += p * qb.z; o[7] += p * qb.w;
    }
    float* orow = n2q + ((size_t)b * Nn + n) * ENC;
    *(float4*)(orow + dA) = make_float4(o[0], o[1], o[2], o[3]);
    *(float4*)(orow + dB) = make_float4(o[4], o[5], o[6], o[7]);
    if (lane == 0) rowmax[b * Nn + n] = mx;
}

// ---------------------------------------------------------------------------
// Fused bvec (softmax over rowmax) + q2n (bvec-weighted sum of nc).
__global__ __launch_bounds__(512) void bvec_q2n_k(const float* __restrict__ rowmax,
                                                  const float* __restrict__ nc,
                                                  float* __restrict__ q2n) {
    __shared__ float red[8];
    __shared__ float bvs[512];
    int b = blockIdx.x, t = threadIdx.x;
    float v = (t < Nn) ? rowmax[b * Nn + t] : -INFINITY;
    float m = v;
    for (int off = 32; off; off >>= 1) m = fmaxf(m, __shfl_xor(m, off, 64));
    if ((t & 63) == 0) red[t >> 6] = m;
    __syncthreads();
    float bm = red[0];
    for (int i = 1; i < 8; ++i) bm = fmaxf(bm, red[i]);
    float e = (t < Nn) ? expf(v - bm) : 0.0f;
    float ssum = e;
    for (int off = 32; off; off >>= 1) ssum += __shfl_xor(ssum, off, 64);
    __syncthreads();
    if ((t & 63) == 0) red[t >> 6] = ssum;
    __syncthreads();
    float tot = 0.f;
    for (int i = 0; i < 8; ++i) tot += red[i];
    bvs[t] = e / tot;
    __syncthreads();
    const float* ncb = nc + (size_t)b * Nn * ENC;
    float acc = 0.f;
    for (int n = 0; n < Nn; ++n) acc = fmaf(bvs[n], ncb[(size_t)n * ENC + t], acc);
    q2n[b * ENC + t] = acc;
}

// ---------------------------------------------------------------------------
// raw[row] = b2 + sum_h tanh(sum_z part[z][row][h] + b1[h]) * W2[h]
__global__ __launch_bounds__(256) void final_reduce_k(const float* __restrict__ part,
                                                      const float* __restrict__ b1p,
                                                      const float* __restrict__ W2p,
                                                      const float* __restrict__ b2p,
                                                      float* __restrict__ raw) {
    constexpr int M = Bn * Nn;
    int wave = threadIdx.x >> 6, lane = threadIdx.x & 63;
    int row = blockIdx.x * 4 + wave;
    if (row >= M) return;
    float v0 = 0.f, v1 = 0.f;
#pragma unroll
    for (int s = 0; s < 4; ++s) {
        const float* pr = part + ((size_t)s * M + row) * 128;
        v0 += pr[lane];
        v1 += pr[lane + 64];
    }
    float p = tanhf(v0 + b1p[lane]) * W2p[lane] + tanhf(v1 + b1p[lane + 64]) * W2p[lane + 64];
    for (int off = 32; off; off >>= 1) p += __shfl_xor(p, off, 64);
    if (lane == 0) raw[row] = p + b2p[0];
}

// ---------------------------------------------------------------------------
__global__ __launch_bounds__(256) void predmax_k(const int* __restrict__ mask,
                                                 const float* __restrict__ raw,
                                                 float* __restrict__ out) {
    int idx = blockIdx.x * 4 + (threadIdx.x >> 6);
    int lane = threadIdx.x & 63;
    if (idx >= Bn * NCn) return;
    int b = idx / NCn, c = idx - b * NCn;
    const int* mrow = mask + ((size_t)b * NCn + c) * Nn;
    const float* rrow = raw + (size_t)b * Nn;
    float mx = -INFINITY;
    for (int n = lane; n < Nn; n += 64) {
        float v = mrow[n] ? rrow[n] : 0.0f;
        if (v == 0.0f) v = -1.0e6f;
        mx = fmaxf(mx, v);
    }
    for (int off = 32; off; off >>= 1) mx = fmaxf(mx, __shfl_xor(mx, off, 64));
    if (lane == 0) out[idx] = mx;
}

}  // namespace

extern "C" void kernel_launch(void* const* d_in, const int* in_sizes, int n_in,
                              void* d_out, int out_size, void* d_ws, size_t ws_size,
                              hipStream_t stream) {
    const float* nodes_glove  = (const float*)d_in[0];
    const float* query_glove  = (const float*)d_in[1];
    const float* adj          = (const float*)d_in[2];
    const int*   nodes_length = (const int*)d_in[3];
    const int*   maskp        = (const int*)d_in[4];
    const float* Wn = (const float*)d_in[5];
    const float* bn = (const float*)d_in[6];
    const float* Wq = (const float*)d_in[7];
    const float* bq = (const float*)d_in[8];
    const float* Wh = (const float*)d_in[9];
    const float* bh = (const float*)d_in[10];
    const float* Wc = (const float*)d_in[11];
    const float* bc = (const float*)d_in[12];
    const float* wa = (const float*)d_in[13];
    const float* W1 = (const float*)d_in[14];
    const float* b1 = (const float*)d_in[15];
    const float* W2 = (const float*)d_in[16];
    const float* b2 = (const float*)d_in[17];
    float* out = (float*)d_out;

    float* ws = (float*)d_ws;
    size_t off = 0;
    auto alloc = [&](size_t n) { float* p = ws + off; off += n; return p; };
    constexpr size_t ME  = (size_t)Bn * Nn * ENC;       // 2,048,000 fp32 elems
    constexpr size_t MEH = ME / 2;
    float* nc   = alloc(ME);
    float* Asum = alloc(ME);       // fp32 adjacency; aliased as n2q after hops
    float* pa   = alloc(ME);       // fp32 partial att logits (lh @ Wc_lo)
    float* Xb   = alloc(ME);       // fp32 X = hm @ Wc_hi (R21)
    float* part = alloc(ME);       // split-K partials (R21: no longer aliases n2q)
    unsigned short* lh0 = (unsigned short*)alloc(MEH);
    unsigned short* lh1 = (unsigned short*)alloc(MEH);
    unsigned short* hm  = (unsigned short*)alloc(MEH);
    float* qc   = alloc((size_t)Bn * Qn * ENC);
    float* rowmax = alloc(Bn * Nn);
    float* q2n    = alloc(Bn * ENC);
    float* raw    = alloc(Bn * Nn);
    float* bhc2   = alloc(512);
    unsigned short* WnT  = (unsigned short*)alloc((size_t)ENC * 320 / 2);
    unsigned short* WqT  = (unsigned short*)alloc((size_t)ENC * 320 / 2);
    unsigned short* WhcT = (unsigned short*)alloc((size_t)1536 * 512 / 2);
    unsigned short* WcHiT = (unsigned short*)alloc((size_t)512 * 512 / 2);
    unsigned short* W1T  = (unsigned short*)alloc((size_t)128 * 2048 / 2);
    alloc(16384);  // tail pad
    float* n2q = Asum;             // after hops

    constexpr int M = Bn * Nn;  // 4000

    // 1. Fused prep: Asum (z=1) + weight transposes (z=0).
    prep_k<<<dim3(2048, 1, 2), 256, 0, stream>>>(adj, Asum, Wn, Wq, Wh, Wc, W1,
                                                 WnT, WqT, WhcT, WcHiT, W1T);

    // 2. Fused input GEMMs + Whc2 = Wh@Wc_hi + bhc2 (601 blocks).
    gemm_in_k<<<dim3(601), 256, 0, stream>>>(nodes_glove, query_glove, Wh, Wc, bh,
                                             WnT, WqT, WcHiT, bn, bq, nodes_length,
                                             nc, lh0, qc, WhcT, bhc2);

    // 3-8. 3 hops x 2 dispatches (R21: att GEMM folded into K1 via Whc2).
    unsigned short* cur = lh0;
    unsigned short* nxt = lh1;
    for (int h = 0; h < 3; ++h) {
        gemm_hop_k<<<dim3(63, 24), 256, 0, stream>>>(cur, WhcT, bh, bhc2,
                                                     nodes_length, hm, pa, Xb);
        upd_att_k<<<dim3(M / 4), 256, 0, stream>>>(Asum, hm, Xb, pa, bc,
                                                   nodes_length, cur, nxt);
        unsigned short* tmp = cur; cur = nxt; nxt = tmp;
    }
    // cur == lh1 == final last_hop.

    // 9-13. Tail.
    sim_fused_k<<<dim3(Bn, 125), 256, 0, stream>>>(cur, qc, wa, nodes_length, n2q, rowmax);
    bvec_q2n_k<<<dim3(Bn), 512, 0, stream>>>(rowmax, nc, q2n);
    gemm_final_k<<<dim3((M + 63) / 64, 2, 4), 256, 0, stream>>>(nc, n2q, q2n, W1T, part);
    final_reduce_k<<<dim3((M + 3) / 4), 256, 0, stream>>>(part, b1, W2, b2, raw);
    predmax_k<<<dim3((Bn * NCn + 3) / 4), 256, 0, stream>>>(maskp, raw, out);
}